// Round 12
// baseline (488.551 us; speedup 1.0000x reference)
//
#include <hip/hip_runtime.h>

#define NNODES 50000
#define BGR 32
#define ROWF 192              // 32 graphs * 6 channels per node row
#define BN_EPS 1e-5f
#define NC 100                // nodes per gemm1 block -> 600 k-values (bf16 s_act, 38.4KB LDS)
#define GSPLITS (NNODES / NC) // 500
#define RGROUPS 16
#define GATHER_BLOCKS 1024    // 2048 measured +143us (L2 thrash, r8); keep 1024

// bf16 helpers: m/agg/partials stored bf16; stats/p2/MLP math fp32
__device__ inline unsigned int bf16rne(float x) {
    unsigned int u = __float_as_uint(x);
    return (u + 0x7FFFu + ((u >> 16) & 1u)) >> 16;
}
__device__ inline unsigned int bf16pack(float a, float b) {
    return bf16rne(a) | (bf16rne(b) << 16);
}
__device__ inline float4 ldrow_bf16(const unsigned short* p) {
    uint2 q = *(const uint2*)p;                 // 4 bf16 = 8B per lane
    float4 v;
    v.x = __uint_as_float(q.x << 16);
    v.y = __uint_as_float(q.x & 0xFFFF0000u);
    v.z = __uint_as_float(q.y << 16);
    v.w = __uint_as_float(q.y & 0xFFFF0000u);
    return v;
}

// ---------- degree / normalization ----------
__global__ void count_deg_kernel(const int* __restrict__ col, int E, int* __restrict__ deg) {
    int e = blockIdx.x * blockDim.x + threadIdx.x;
    if (e < E) atomicAdd(&deg[col[e]], 1);
}

__global__ void make_dis_kernel(const int* __restrict__ deg, float* __restrict__ dis, int N) {
    int n = blockIdx.x * blockDim.x + threadIdx.x;
    if (n < N) dis[n] = rsqrtf((float)(deg[n] + 1));   // +1 self loop
}

// ---------- 3-phase scan: deg -> offs (exclusive), cursor copy ----------
__global__ __launch_bounds__(256) void scanA_kernel(const int* __restrict__ deg, int* __restrict__ bsum, int N) {
    __shared__ int lds[256];
    int i = blockIdx.x * 256 + threadIdx.x;
    lds[threadIdx.x] = (i < N) ? deg[i] : 0;
    __syncthreads();
    for (int off = 128; off > 0; off >>= 1) {
        if (threadIdx.x < off) lds[threadIdx.x] += lds[threadIdx.x + off];
        __syncthreads();
    }
    if (threadIdx.x == 0) bsum[blockIdx.x] = lds[0];
}

__global__ __launch_bounds__(256) void scanB_kernel(const int* __restrict__ bsum, int* __restrict__ bbase,
                                                    int* __restrict__ offsN, int nblk) {
    __shared__ int lds[256];
    int t = threadIdx.x;
    int v = (t < nblk) ? bsum[t] : 0;
    lds[t] = v;
    __syncthreads();
    for (int off = 1; off < 256; off <<= 1) {
        int u = (t >= off) ? lds[t - off] : 0;
        __syncthreads();
        lds[t] += u;
        __syncthreads();
    }
    if (t < nblk) bbase[t] = lds[t] - v;   // exclusive base per block
    if (t == 255) offsN[0] = lds[255];     // total -> offs[N]
}

__global__ __launch_bounds__(256) void scanC_kernel(const int* __restrict__ deg, const int* __restrict__ bbase,
                                                    int* __restrict__ offs, int* __restrict__ cursor, int N) {
    __shared__ int lds[256];
    int i = blockIdx.x * 256 + threadIdx.x;
    int t = threadIdx.x;
    int v = (i < N) ? deg[i] : 0;
    lds[t] = v;
    __syncthreads();
    for (int off = 1; off < 256; off <<= 1) {
        int u = (t >= off) ? lds[t - off] : 0;
        __syncthreads();
        lds[t] += u;
        __syncthreads();
    }
    if (i < N) {
        int excl = bbase[blockIdx.x] + lds[t] - v;
        offs[i] = excl;
        cursor[i] = excl;
    }
}

// ---------- CSR fill: (src, weight) packed 8B per edge, grouped by dest ----------
__global__ void fill_csr_kernel(const int* __restrict__ row, const int* __restrict__ col,
                                const float* __restrict__ dis, int* __restrict__ cursor,
                                int2* __restrict__ csr_rw, int E) {
    int e = blockIdx.x * blockDim.x + threadIdx.x;
    if (e >= E) return;
    int r = row[e], c = col[e];
    int pos = atomicAdd(&cursor[c], 1);
    csr_rw[pos] = make_int2(r, __float_as_int(dis[r] * dis[c]));
}

// ---------- T1: x [B][N][3] -> m1 [N][32*6] node-major bf16, m1 = x @ W1 ----------
__global__ __launch_bounds__(256) void t1_kernel(const float* __restrict__ x,
                                                 const float* __restrict__ W,
                                                 unsigned short* __restrict__ m, int N) {
    __shared__ float xt[BGR][ROWF];   // 64 nodes * 3 floats per graph = 24KB
    __shared__ float sW[18];
    int tid = threadIdx.x;
    if (tid < 18) sW[tid] = W[tid];
    int n0 = blockIdx.x * 64;
    int nval = N - n0; if (nval > 64) nval = 64;
    int lim = nval * 3;
    for (int b = 0; b < BGR; b++) {
        if (tid < lim) xt[b][tid] = x[((size_t)b * N + n0) * 3 + tid];
    }
    __syncthreads();
    for (int i = 0; i < 8; i++) {
        int pi = i * 256 + tid;
        int nl = pi >> 5, b = pi & 31;
        if (nl < nval) {
            float h0 = xt[b][nl * 3], h1 = xt[b][nl * 3 + 1], h2 = xt[b][nl * 3 + 2];
            float o[6];
            #pragma unroll
            for (int j = 0; j < 6; j++)
                o[j] = h0 * sW[j] + h1 * sW[6 + j] + h2 * sW[12 + j];
            unsigned int* mp = (unsigned int*)(m + (size_t)(n0 + nl) * ROWF + b * 6);
            mp[0] = bf16pack(o[0], o[1]);
            mp[1] = bf16pack(o[2], o[3]);
            mp[2] = bf16pack(o[4], o[5]);
        }
    }
}

// ---------- T2/T3: m(bf16) = relu(bn(agg bf16, exact stats)) @ W ----------
__global__ __launch_bounds__(256) void t23_kernel(const unsigned short* __restrict__ agg,
                                                  const float* __restrict__ stats,
                                                  const float* __restrict__ gam,
                                                  const float* __restrict__ bet,
                                                  const float* __restrict__ W,
                                                  unsigned short* __restrict__ m, int NB) {
    __shared__ float sW[36];
    int tid = threadIdx.x;
    if (tid < 36) sW[tid] = W[tid];
    __syncthreads();
    float inv = 1.f / (float)NB;
    float sa[6], sc[6];
    #pragma unroll
    for (int j = 0; j < 6; j++) {
        float mu = stats[j] * inv;
        float var = stats[6 + j] * inv - mu * mu;
        float rs = rsqrtf(var + BN_EPS);
        float a = gam[j] * rs;
        sa[j] = a; sc[j] = bet[j] - mu * a;
    }
    size_t i = (size_t)blockIdx.x * 256 + tid;   // (n,b) pair; 6 bf16 = 12B, 4-aligned
    if (i >= (size_t)NB) return;
    const unsigned int* ap = (const unsigned int*)(agg + i * 6);
    unsigned int q0 = ap[0], q1 = ap[1], q2 = ap[2];
    float h[6];
    h[0] = __uint_as_float(q0 << 16); h[1] = __uint_as_float(q0 & 0xFFFF0000u);
    h[2] = __uint_as_float(q1 << 16); h[3] = __uint_as_float(q1 & 0xFFFF0000u);
    h[4] = __uint_as_float(q2 << 16); h[5] = __uint_as_float(q2 & 0xFFFF0000u);
    #pragma unroll
    for (int k = 0; k < 6; k++) {
        float v = fmaf(sa[k], h[k], sc[k]);
        h[k] = v > 0.f ? v : 0.f;
    }
    float o[6];
    #pragma unroll
    for (int j = 0; j < 6; j++) {
        float t = 0.f;
        #pragma unroll
        for (int k = 0; k < 6; k++) t = fmaf(h[k], sW[k * 6 + j], t);
        o[j] = t;
    }
    unsigned int* mp = (unsigned int*)(m + i * 6);
    mp[0] = bf16pack(o[0], o[1]);
    mp[1] = bf16pack(o[2], o[3]);
    mp[2] = bf16pack(o[4], o[5]);
}

// ---------- gather: wave handles TWO nodes (ILP x2); bf16 rows in AND out; fused exact BN stats ----------
__global__ __launch_bounds__(256) void gather_kernel(const unsigned short* __restrict__ m,
                                                     const int* __restrict__ offs,
                                                     const int2* __restrict__ csr_rw,
                                                     const float* __restrict__ dis,
                                                     unsigned short* __restrict__ agg,
                                                     float* __restrict__ stats_out, int N) {
    int tid = threadIdx.x;
    int wv = tid >> 6, lane = tid & 63;
    bool lact = lane < 48;                       // 48 lanes x 4 ch = 192 channels
    int loff = lane * 4;
    float4 ssum = make_float4(0.f, 0.f, 0.f, 0.f);
    float4 ssq  = make_float4(0.f, 0.f, 0.f, 0.f);
    int ngrp = (N + 7) >> 3;                     // 8 nodes per group (4 waves x 2)
    for (int grp = blockIdx.x; grp < ngrp; grp += gridDim.x) {
        int n0 = grp * 8 + wv;
        int n1 = n0 + 4;
        if (n0 >= N) continue;
        bool v1 = (n1 < N);
        float d0 = dis[n0];
        float d1 = v1 ? dis[n1] : 0.f;
        int s0 = offs[n0], e0 = offs[n0 + 1];
        int s1 = v1 ? offs[n1] : 0, e1 = v1 ? offs[n1 + 1] : 0;
        float4 acc0 = make_float4(0.f, 0.f, 0.f, 0.f);
        float4 acc1 = make_float4(0.f, 0.f, 0.f, 0.f);
        if (lact) {
            const float4 va = ldrow_bf16(m + (size_t)n0 * ROWF + loff);
            const float4 vb = ldrow_bf16(m + (size_t)(v1 ? n1 : n0) * ROWF + loff);
            float wa = d0 * d0, wb = d1 * d1;
            acc0.x = wa * va.x; acc0.y = wa * va.y; acc0.z = wa * va.z; acc0.w = wa * va.w;
            acc1.x = wb * vb.x; acc1.y = wb * vb.y; acc1.z = wb * vb.z; acc1.w = wb * vb.w;
        }
        int p0 = s0, p1 = s1;
        int len0 = e0 - s0, len1 = e1 - s1;
        int iters = len0 > len1 ? len0 : len1;
        for (int it = 0; it < iters; it++) {
            int  r0 = n0; float w0 = 0.f;
            int  r1 = v1 ? n1 : n0; float w1 = 0.f;
            if (p0 < e0) { int2 t0 = csr_rw[p0]; r0 = t0.x; w0 = __int_as_float(t0.y); }
            if (p1 < e1) { int2 t1 = csr_rw[p1]; r1 = t1.x; w1 = __int_as_float(t1.y); }
            if (lact) {
                const float4 va = ldrow_bf16(m + (size_t)r0 * ROWF + loff);
                const float4 vb = ldrow_bf16(m + (size_t)r1 * ROWF + loff);
                acc0.x = fmaf(w0, va.x, acc0.x); acc0.y = fmaf(w0, va.y, acc0.y);
                acc0.z = fmaf(w0, va.z, acc0.z); acc0.w = fmaf(w0, va.w, acc0.w);
                acc1.x = fmaf(w1, vb.x, acc1.x); acc1.y = fmaf(w1, vb.y, acc1.y);
                acc1.z = fmaf(w1, vb.z, acc1.z); acc1.w = fmaf(w1, vb.w, acc1.w);
            }
            p0++; p1++;
        }
        if (lact) {
            *(uint2*)(agg + (size_t)n0 * ROWF + loff) =
                make_uint2(bf16pack(acc0.x, acc0.y), bf16pack(acc0.z, acc0.w));
            if (v1)
                *(uint2*)(agg + (size_t)n1 * ROWF + loff) =
                    make_uint2(bf16pack(acc1.x, acc1.y), bf16pack(acc1.z, acc1.w));
        }
        ssum.x += acc0.x + acc1.x; ssum.y += acc0.y + acc1.y;
        ssum.z += acc0.z + acc1.z; ssum.w += acc0.w + acc1.w;
        ssq.x = fmaf(acc0.x, acc0.x, fmaf(acc1.x, acc1.x, ssq.x));
        ssq.y = fmaf(acc0.y, acc0.y, fmaf(acc1.y, acc1.y, ssq.y));
        ssq.z = fmaf(acc0.z, acc0.z, fmaf(acc1.z, acc1.z, ssq.z));
        ssq.w = fmaf(acc0.w, acc0.w, fmaf(acc1.w, acc1.w, ssq.w));
    }
    // lane l, comp q holds channel j=(4l+q)%6 : constant along lane stride 3
    float vals[8] = {ssum.x, ssum.y, ssum.z, ssum.w, ssq.x, ssq.y, ssq.z, ssq.w};
    #pragma unroll
    for (int q = 0; q < 8; q++) {
        vals[q] += __shfl_down(vals[q], 24, 64);
        vals[q] += __shfl_down(vals[q], 12, 64);
        vals[q] += __shfl_down(vals[q], 6, 64);
        vals[q] += __shfl_down(vals[q], 3, 64);
    }
    __shared__ float red[4][3][8];
    if (lane < 3) {
        #pragma unroll
        for (int q = 0; q < 8; q++) red[wv][lane][q] = vals[q];
    }
    __syncthreads();
    if (tid < 24) {
        int l0 = tid >> 3, qq = tid & 7;
        float v = red[0][l0][qq] + red[1][l0][qq] + red[2][l0][qq] + red[3][l0][qq];
        int j = (4 * l0 + (qq & 3)) % 6;
        atomicAdd(&stats_out[(qq < 4 ? 0 : 6) + j], v);
    }
}

// ---------- GEMM1 v2: bf16 s_act (NC=100), bf16 partials; waves own 8 graphs ----------
__global__ __launch_bounds__(256) void gemm1_kernel(const unsigned short* __restrict__ agg3,
                                                    const float* __restrict__ stats,
                                                    const float* __restrict__ gam,
                                                    const float* __restrict__ bet,
                                                    const float* __restrict__ lw1,
                                                    unsigned int* __restrict__ partials, int NB) {
    __shared__ unsigned int s_act[NC * ROWF / 2];   // 9600 uints = 38.4KB (bf16 pairs)
    int tid = threadIdx.x;
    float inv = 1.f / (float)NB;
    float sa[6], sc[6];
    #pragma unroll
    for (int j = 0; j < 6; j++) {
        float mu = stats[j] * inv;
        float var = stats[6 + j] * inv - mu * mu;
        float rs = rsqrtf(var + BN_EPS);
        float a = gam[j] * rs;
        sa[j] = a; sc[j] = bet[j] - mu * a;
    }
    int n0 = blockIdx.x * NC;
    const unsigned int* ab = (const unsigned int*)(agg3 + (size_t)n0 * ROWF);
    for (int idx = tid; idx < NC * ROWF / 2; idx += 256) {
        unsigned int q = ab[idx];
        float v0 = __uint_as_float(q << 16);
        float v1 = __uint_as_float(q & 0xFFFF0000u);
        int j0 = (2 * idx) % 6;                   // even; j1 = j0+1
        float t0 = fmaf(sa[j0], v0, sc[j0]);
        float t1 = fmaf(sa[j0 + 1], v1, sc[j0 + 1]);
        t0 = t0 > 0.f ? t0 : 0.f;
        t1 = t1 > 0.f ? t1 : 0.f;
        s_act[idx] = bf16pack(t0, t1);
    }
    __syncthreads();
    int wv = tid >> 6, lane = tid & 63;
    int b0 = wv * 8;
    float4 acc[8];
    #pragma unroll
    for (int i = 0; i < 8; i++) acc[i] = make_float4(0.f, 0.f, 0.f, 0.f);
    const float* wbase = lw1 + (size_t)n0 * 6 * 256 + 4 * lane;
    for (int nl = 0; nl < NC; nl++) {
        float4 w6[6];
        #pragma unroll
        for (int j = 0; j < 6; j++)
            w6[j] = *(const float4*)(wbase + ((size_t)nl * 6 + j) * 256);
        const unsigned int* hu = &s_act[nl * (ROWF / 2) + b0 * 3];
        #pragma unroll
        for (int bb = 0; bb < 8; bb++) {
            unsigned int q0 = hu[bb * 3], q1 = hu[bb * 3 + 1], q2 = hu[bb * 3 + 2];
            float h0 = __uint_as_float(q0 << 16), h1 = __uint_as_float(q0 & 0xFFFF0000u);
            float h2 = __uint_as_float(q1 << 16), h3 = __uint_as_float(q1 & 0xFFFF0000u);
            float h4 = __uint_as_float(q2 << 16), h5 = __uint_as_float(q2 & 0xFFFF0000u);
            float4 a = acc[bb];
            a.x = fmaf(h0, w6[0].x, a.x); a.y = fmaf(h0, w6[0].y, a.y);
            a.z = fmaf(h0, w6[0].z, a.z); a.w = fmaf(h0, w6[0].w, a.w);
            a.x = fmaf(h1, w6[1].x, a.x); a.y = fmaf(h1, w6[1].y, a.y);
            a.z = fmaf(h1, w6[1].z, a.z); a.w = fmaf(h1, w6[1].w, a.w);
            a.x = fmaf(h2, w6[2].x, a.x); a.y = fmaf(h2, w6[2].y, a.y);
            a.z = fmaf(h2, w6[2].z, a.z); a.w = fmaf(h2, w6[2].w, a.w);
            a.x = fmaf(h3, w6[3].x, a.x); a.y = fmaf(h3, w6[3].y, a.y);
            a.z = fmaf(h3, w6[3].z, a.z); a.w = fmaf(h3, w6[3].w, a.w);
            a.x = fmaf(h4, w6[4].x, a.x); a.y = fmaf(h4, w6[4].y, a.y);
            a.z = fmaf(h4, w6[4].z, a.z); a.w = fmaf(h4, w6[4].w, a.w);
            a.x = fmaf(h5, w6[5].x, a.x); a.y = fmaf(h5, w6[5].y, a.y);
            a.z = fmaf(h5, w6[5].z, a.z); a.w = fmaf(h5, w6[5].w, a.w);
            acc[bb] = a;
        }
    }
    // write bf16 partials: row (split*32 + graph) of 256 bf16 = 128 uints; lane owns uints [2*lane, 2*lane+1]
    #pragma unroll
    for (int bb = 0; bb < 8; bb++) {
        unsigned int* prow = partials + (((size_t)blockIdx.x * BGR) + b0 + bb) * 128;
        *(uint2*)&prow[2 * lane] = make_uint2(bf16pack(acc[bb].x, acc[bb].y),
                                             bf16pack(acc[bb].z, acc[bb].w));
    }
}

// ---------- reduce bf16 partials[GSPLITS][32*128u] -> p2[RGROUPS][32*256] fp32 ----------
__global__ __launch_bounds__(256) void reduce1_kernel(const unsigned int* __restrict__ partials,
                                                      float* __restrict__ p2) {
    int o = blockIdx.x * 256 + threadIdx.x;   // uint index in [0, 4096); grid.x = 16
    int g = blockIdx.y;                        // 0..15
    float a0 = 0.f, a1 = 0.f;
    for (int s = g; s < GSPLITS; s += RGROUPS) {
        unsigned int q = partials[(size_t)s * (BGR * 128) + o];
        a0 += __uint_as_float(q << 16);
        a1 += __uint_as_float(q & 0xFFFF0000u);
    }
    p2[(size_t)g * (BGR * 256) + 2 * o]     = a0;
    p2[(size_t)g * (BGR * 256) + 2 * o + 1] = a1;
}

// ---------- tail: sum 16 groups + lb1/relu, then 256->128->64->32 ----------
__global__ __launch_bounds__(1024) void tail_kernel(const float* __restrict__ p2,
                                                    const float* __restrict__ lb1,
                                                    const float* __restrict__ lw2, const float* __restrict__ lb2,
                                                    const float* __restrict__ lw3, const float* __restrict__ lb3,
                                                    const float* __restrict__ lw4, const float* __restrict__ lb4,
                                                    float* __restrict__ out) {
    __shared__ float red[4][256];
    __shared__ float s1[256], s2[128], s3[64];
    int b = blockIdx.x;
    int tid = threadIdx.x;
    int c = tid & 255, sg = tid >> 8;
    float a = 0.f;
    for (int g = sg; g < RGROUPS; g += 4)
        a += p2[(size_t)g * (BGR * 256) + b * 256 + c];
    red[sg][c] = a;
    __syncthreads();
    if (tid < 256) {
        float v = red[0][tid] + red[1][tid] + red[2][tid] + red[3][tid] + lb1[tid];
        s1[tid] = v > 0.f ? v : 0.f;
    }
    __syncthreads();
    if (tid < 128) {
        float acc = lb2[tid];
        for (int k = 0; k < 256; k++) acc += s1[k] * lw2[k * 128 + tid];
        s2[tid] = acc > 0.f ? acc : 0.f;
    }
    __syncthreads();
    if (tid < 64) {
        float acc = lb3[tid];
        for (int k = 0; k < 128; k++) acc += s2[k] * lw3[k * 64 + tid];
        s3[tid] = acc > 0.f ? acc : 0.f;
    }
    __syncthreads();
    if (tid < 32) {
        float acc = lb4[tid];
        for (int k = 0; k < 64; k++) acc += s3[k] * lw4[k * 32 + tid];
        out[b * 32 + tid] = acc;
    }
}

extern "C" void kernel_launch(void* const* d_in, const int* in_sizes, int n_in,
                              void* d_out, int out_size, void* d_ws, size_t ws_size,
                              hipStream_t stream) {
    const float* x   = (const float*)d_in[0];
    const int* edge  = (const int*)d_in[1];
    const float* W1  = (const float*)d_in[2];
    const float* g1  = (const float*)d_in[4];
    const float* be1 = (const float*)d_in[5];
    const float* W2  = (const float*)d_in[6];
    const float* g2  = (const float*)d_in[8];
    const float* be2 = (const float*)d_in[9];
    const float* W3  = (const float*)d_in[10];
    const float* g3  = (const float*)d_in[12];
    const float* be3 = (const float*)d_in[13];
    const float* lw1 = (const float*)d_in[14];
    const float* lb1 = (const float*)d_in[15];
    const float* lw2 = (const float*)d_in[16];
    const float* lb2 = (const float*)d_in[17];
    const float* lw3 = (const float*)d_in[18];
    const float* lb3 = (const float*)d_in[19];
    const float* lw4 = (const float*)d_in[20];
    const float* lb4 = (const float*)d_in[21];

    const int E = in_sizes[1] / 2;
    const int N = NNODES;
    const int B = in_sizes[0] / (N * 3);
    const int NB = B * N;
    const int nblk = (N + 255) / 256;

    char* ws = (char*)d_ws;
    size_t rowShorts = (size_t)N * ROWF * sizeof(unsigned short);  // 19.2 MB per bf16 buffer
    unsigned short* aggbuf = (unsigned short*)ws;
    unsigned short* mbuf   = (unsigned short*)(ws + rowShorts);
    unsigned int* partials = (unsigned int*)(ws + 2 * rowShorts);  // 500*32*128u = 8.2 MB
    char* p = ws + 2 * rowShorts + (size_t)GSPLITS * BGR * 128 * 4;
    float* dis    = (float*)p;  p += (size_t)N * 4;
    int*   deg    = (int*)p;    p += (size_t)N * 4;
    int*   offs   = (int*)p;    p += (size_t)(N + 1) * 4;
    int*   cursor = (int*)p;    p += (size_t)N * 4;
    int*   bsum   = (int*)p;    p += 256 * 4;
    int*   bbase  = (int*)p;    p += 256 * 4;
    int2*  csr_rw = (int2*)p;   p += (size_t)E * 8;
    float* stats  = (float*)p;  p += 48 * 4;
    float* p2     = (float*)p;  p += (size_t)RGROUPS * BGR * 256 * 4;
    float* stats1 = stats, *stats2 = stats + 16, *stats3 = stats + 32;

    const int T = 256;

    hipMemsetAsync(deg, 0, (size_t)N * 4, stream);
    hipMemsetAsync(stats, 0, 48 * 4, stream);
    count_deg_kernel<<<(E + T - 1) / T, T, 0, stream>>>(edge + E, E, deg);
    make_dis_kernel<<<(N + T - 1) / T, T, 0, stream>>>(deg, dis, N);
    scanA_kernel<<<nblk, T, 0, stream>>>(deg, bsum, N);
    scanB_kernel<<<1, T, 0, stream>>>(bsum, bbase, offs + N, nblk);
    scanC_kernel<<<nblk, T, 0, stream>>>(deg, bbase, offs, cursor, N);
    fill_csr_kernel<<<(E + T - 1) / T, T, 0, stream>>>(edge, edge + E, dis, cursor, csr_rw, E);

    // layer 1: m1 = x@W1 (bf16) ; agg1 = S m1 (bf16, exact stats)
    t1_kernel<<<(N + 63) / 64, T, 0, stream>>>(x, W1, mbuf, N);
    gather_kernel<<<GATHER_BLOCKS, T, 0, stream>>>(mbuf, offs, csr_rw, dis, aggbuf, stats1, N);
    // layer 2
    t23_kernel<<<(NB + T - 1) / T, T, 0, stream>>>(aggbuf, stats1, g1, be1, W2, mbuf, NB);
    gather_kernel<<<GATHER_BLOCKS, T, 0, stream>>>(mbuf, offs, csr_rw, dis, aggbuf, stats2, N);
    // layer 3
    t23_kernel<<<(NB + T - 1) / T, T, 0, stream>>>(aggbuf, stats2, g2, be2, W3, mbuf, NB);
    gather_kernel<<<GATHER_BLOCKS, T, 0, stream>>>(mbuf, offs, csr_rw, dis, aggbuf, stats3, N);

    // MLP head (bf16 agg3 + bf16 partials; p2/tail fp32)
    gemm1_kernel<<<GSPLITS, T, 0, stream>>>(aggbuf, stats3, g3, be3, lw1, partials, NB);
    reduce1_kernel<<<dim3(16, RGROUPS), T, 0, stream>>>(partials, p2);
    tail_kernel<<<B, 1024, 0, stream>>>(p2, lb1, lw2, lb2, lw3, lb3, lw4, lb4, (float*)d_out);
}

// Round 13
// 463.752 us; speedup vs baseline: 1.0535x; 1.0535x over previous
//
#include <hip/hip_runtime.h>

#define NNODES 50000
#define BGR 32
#define ROWF 192              // 32 graphs * 6 channels per node row
#define BN_EPS 1e-5f
#define NC 50                 // nodes per gemm1 block; 100 measured +50us (occupancy drop, r12)
#define GSPLITS (NNODES / NC) // 1000
#define RGROUPS 16
#define GATHER_BLOCKS 1024    // 2048 measured +143us (L2 thrash, r8); keep 1024

// bf16 helpers: m/agg/partials stored bf16; stats/p2/MLP math fp32
__device__ inline unsigned int bf16rne(float x) {
    unsigned int u = __float_as_uint(x);
    return (u + 0x7FFFu + ((u >> 16) & 1u)) >> 16;
}
__device__ inline unsigned int bf16pack(float a, float b) {
    return bf16rne(a) | (bf16rne(b) << 16);
}
__device__ inline float4 ldrow_bf16(const unsigned short* p) {
    uint2 q = *(const uint2*)p;                 // 4 bf16 = 8B per lane
    float4 v;
    v.x = __uint_as_float(q.x << 16);
    v.y = __uint_as_float(q.x & 0xFFFF0000u);
    v.z = __uint_as_float(q.y << 16);
    v.w = __uint_as_float(q.y & 0xFFFF0000u);
    return v;
}

// ---------- degree / normalization ----------
__global__ void count_deg_kernel(const int* __restrict__ col, int E, int* __restrict__ deg) {
    int e = blockIdx.x * blockDim.x + threadIdx.x;
    if (e < E) atomicAdd(&deg[col[e]], 1);
}

__global__ void make_dis_kernel(const int* __restrict__ deg, float* __restrict__ dis, int N) {
    int n = blockIdx.x * blockDim.x + threadIdx.x;
    if (n < N) dis[n] = rsqrtf((float)(deg[n] + 1));   // +1 self loop
}

// ---------- 3-phase scan: deg -> offs (exclusive), cursor copy ----------
__global__ __launch_bounds__(256) void scanA_kernel(const int* __restrict__ deg, int* __restrict__ bsum, int N) {
    __shared__ int lds[256];
    int i = blockIdx.x * 256 + threadIdx.x;
    lds[threadIdx.x] = (i < N) ? deg[i] : 0;
    __syncthreads();
    for (int off = 128; off > 0; off >>= 1) {
        if (threadIdx.x < off) lds[threadIdx.x] += lds[threadIdx.x + off];
        __syncthreads();
    }
    if (threadIdx.x == 0) bsum[blockIdx.x] = lds[0];
}

__global__ __launch_bounds__(256) void scanB_kernel(const int* __restrict__ bsum, int* __restrict__ bbase,
                                                    int* __restrict__ offsN, int nblk) {
    __shared__ int lds[256];
    int t = threadIdx.x;
    int v = (t < nblk) ? bsum[t] : 0;
    lds[t] = v;
    __syncthreads();
    for (int off = 1; off < 256; off <<= 1) {
        int u = (t >= off) ? lds[t - off] : 0;
        __syncthreads();
        lds[t] += u;
        __syncthreads();
    }
    if (t < nblk) bbase[t] = lds[t] - v;   // exclusive base per block
    if (t == 255) offsN[0] = lds[255];     // total -> offs[N]
}

__global__ __launch_bounds__(256) void scanC_kernel(const int* __restrict__ deg, const int* __restrict__ bbase,
                                                    int* __restrict__ offs, int* __restrict__ cursor, int N) {
    __shared__ int lds[256];
    int i = blockIdx.x * 256 + threadIdx.x;
    int t = threadIdx.x;
    int v = (i < N) ? deg[i] : 0;
    lds[t] = v;
    __syncthreads();
    for (int off = 1; off < 256; off <<= 1) {
        int u = (t >= off) ? lds[t - off] : 0;
        __syncthreads();
        lds[t] += u;
        __syncthreads();
    }
    if (i < N) {
        int excl = bbase[blockIdx.x] + lds[t] - v;
        offs[i] = excl;
        cursor[i] = excl;
    }
}

// ---------- CSR fill: (src, weight) packed 8B per edge, grouped by dest ----------
__global__ void fill_csr_kernel(const int* __restrict__ row, const int* __restrict__ col,
                                const float* __restrict__ dis, int* __restrict__ cursor,
                                int2* __restrict__ csr_rw, int E) {
    int e = blockIdx.x * blockDim.x + threadIdx.x;
    if (e >= E) return;
    int r = row[e], c = col[e];
    int pos = atomicAdd(&cursor[c], 1);
    csr_rw[pos] = make_int2(r, __float_as_int(dis[r] * dis[c]));
}

// ---------- T1: x [B][N][3] -> m1 [N][32*6] node-major bf16, m1 = x @ W1 ----------
__global__ __launch_bounds__(256) void t1_kernel(const float* __restrict__ x,
                                                 const float* __restrict__ W,
                                                 unsigned short* __restrict__ m, int N) {
    __shared__ float xt[BGR][ROWF];   // 64 nodes * 3 floats per graph = 24KB
    __shared__ float sW[18];
    int tid = threadIdx.x;
    if (tid < 18) sW[tid] = W[tid];
    int n0 = blockIdx.x * 64;
    int nval = N - n0; if (nval > 64) nval = 64;
    int lim = nval * 3;
    for (int b = 0; b < BGR; b++) {
        if (tid < lim) xt[b][tid] = x[((size_t)b * N + n0) * 3 + tid];
    }
    __syncthreads();
    for (int i = 0; i < 8; i++) {
        int pi = i * 256 + tid;
        int nl = pi >> 5, b = pi & 31;
        if (nl < nval) {
            float h0 = xt[b][nl * 3], h1 = xt[b][nl * 3 + 1], h2 = xt[b][nl * 3 + 2];
            float o[6];
            #pragma unroll
            for (int j = 0; j < 6; j++)
                o[j] = h0 * sW[j] + h1 * sW[6 + j] + h2 * sW[12 + j];
            unsigned int* mp = (unsigned int*)(m + (size_t)(n0 + nl) * ROWF + b * 6);
            mp[0] = bf16pack(o[0], o[1]);
            mp[1] = bf16pack(o[2], o[3]);
            mp[2] = bf16pack(o[4], o[5]);
        }
    }
}

// ---------- T2/T3: m(bf16) = relu(bn(agg bf16, exact stats)) @ W ----------
__global__ __launch_bounds__(256) void t23_kernel(const unsigned short* __restrict__ agg,
                                                  const float* __restrict__ stats,
                                                  const float* __restrict__ gam,
                                                  const float* __restrict__ bet,
                                                  const float* __restrict__ W,
                                                  unsigned short* __restrict__ m, int NB) {
    __shared__ float sW[36];
    int tid = threadIdx.x;
    if (tid < 36) sW[tid] = W[tid];
    __syncthreads();
    float inv = 1.f / (float)NB;
    float sa[6], sc[6];
    #pragma unroll
    for (int j = 0; j < 6; j++) {
        float mu = stats[j] * inv;
        float var = stats[6 + j] * inv - mu * mu;
        float rs = rsqrtf(var + BN_EPS);
        float a = gam[j] * rs;
        sa[j] = a; sc[j] = bet[j] - mu * a;
    }
    size_t i = (size_t)blockIdx.x * 256 + tid;   // (n,b) pair; 6 bf16 = 12B, 4-aligned
    if (i >= (size_t)NB) return;
    const unsigned int* ap = (const unsigned int*)(agg + i * 6);
    unsigned int q0 = ap[0], q1 = ap[1], q2 = ap[2];
    float h[6];
    h[0] = __uint_as_float(q0 << 16); h[1] = __uint_as_float(q0 & 0xFFFF0000u);
    h[2] = __uint_as_float(q1 << 16); h[3] = __uint_as_float(q1 & 0xFFFF0000u);
    h[4] = __uint_as_float(q2 << 16); h[5] = __uint_as_float(q2 & 0xFFFF0000u);
    #pragma unroll
    for (int k = 0; k < 6; k++) {
        float v = fmaf(sa[k], h[k], sc[k]);
        h[k] = v > 0.f ? v : 0.f;
    }
    float o[6];
    #pragma unroll
    for (int j = 0; j < 6; j++) {
        float t = 0.f;
        #pragma unroll
        for (int k = 0; k < 6; k++) t = fmaf(h[k], sW[k * 6 + j], t);
        o[j] = t;
    }
    unsigned int* mp = (unsigned int*)(m + i * 6);
    mp[0] = bf16pack(o[0], o[1]);
    mp[1] = bf16pack(o[2], o[3]);
    mp[2] = bf16pack(o[4], o[5]);
}

// ---------- gather: wave handles TWO nodes (ILP x2); bf16 rows in AND out; fused exact BN stats ----------
__global__ __launch_bounds__(256) void gather_kernel(const unsigned short* __restrict__ m,
                                                     const int* __restrict__ offs,
                                                     const int2* __restrict__ csr_rw,
                                                     const float* __restrict__ dis,
                                                     unsigned short* __restrict__ agg,
                                                     float* __restrict__ stats_out, int N) {
    int tid = threadIdx.x;
    int wv = tid >> 6, lane = tid & 63;
    bool lact = lane < 48;                       // 48 lanes x 4 ch = 192 channels
    int loff = lane * 4;
    float4 ssum = make_float4(0.f, 0.f, 0.f, 0.f);
    float4 ssq  = make_float4(0.f, 0.f, 0.f, 0.f);
    int ngrp = (N + 7) >> 3;                     // 8 nodes per group (4 waves x 2)
    for (int grp = blockIdx.x; grp < ngrp; grp += gridDim.x) {
        int n0 = grp * 8 + wv;
        int n1 = n0 + 4;
        if (n0 >= N) continue;
        bool v1 = (n1 < N);
        float d0 = dis[n0];
        float d1 = v1 ? dis[n1] : 0.f;
        int s0 = offs[n0], e0 = offs[n0 + 1];
        int s1 = v1 ? offs[n1] : 0, e1 = v1 ? offs[n1 + 1] : 0;
        float4 acc0 = make_float4(0.f, 0.f, 0.f, 0.f);
        float4 acc1 = make_float4(0.f, 0.f, 0.f, 0.f);
        if (lact) {
            const float4 va = ldrow_bf16(m + (size_t)n0 * ROWF + loff);
            const float4 vb = ldrow_bf16(m + (size_t)(v1 ? n1 : n0) * ROWF + loff);
            float wa = d0 * d0, wb = d1 * d1;
            acc0.x = wa * va.x; acc0.y = wa * va.y; acc0.z = wa * va.z; acc0.w = wa * va.w;
            acc1.x = wb * vb.x; acc1.y = wb * vb.y; acc1.z = wb * vb.z; acc1.w = wb * vb.w;
        }
        int p0 = s0, p1 = s1;
        int len0 = e0 - s0, len1 = e1 - s1;
        int iters = len0 > len1 ? len0 : len1;
        for (int it = 0; it < iters; it++) {
            int  r0 = n0; float w0 = 0.f;
            int  r1 = v1 ? n1 : n0; float w1 = 0.f;
            if (p0 < e0) { int2 t0 = csr_rw[p0]; r0 = t0.x; w0 = __int_as_float(t0.y); }
            if (p1 < e1) { int2 t1 = csr_rw[p1]; r1 = t1.x; w1 = __int_as_float(t1.y); }
            if (lact) {
                const float4 va = ldrow_bf16(m + (size_t)r0 * ROWF + loff);
                const float4 vb = ldrow_bf16(m + (size_t)r1 * ROWF + loff);
                acc0.x = fmaf(w0, va.x, acc0.x); acc0.y = fmaf(w0, va.y, acc0.y);
                acc0.z = fmaf(w0, va.z, acc0.z); acc0.w = fmaf(w0, va.w, acc0.w);
                acc1.x = fmaf(w1, vb.x, acc1.x); acc1.y = fmaf(w1, vb.y, acc1.y);
                acc1.z = fmaf(w1, vb.z, acc1.z); acc1.w = fmaf(w1, vb.w, acc1.w);
            }
            p0++; p1++;
        }
        if (lact) {
            *(uint2*)(agg + (size_t)n0 * ROWF + loff) =
                make_uint2(bf16pack(acc0.x, acc0.y), bf16pack(acc0.z, acc0.w));
            if (v1)
                *(uint2*)(agg + (size_t)n1 * ROWF + loff) =
                    make_uint2(bf16pack(acc1.x, acc1.y), bf16pack(acc1.z, acc1.w));
        }
        ssum.x += acc0.x + acc1.x; ssum.y += acc0.y + acc1.y;
        ssum.z += acc0.z + acc1.z; ssum.w += acc0.w + acc1.w;
        ssq.x = fmaf(acc0.x, acc0.x, fmaf(acc1.x, acc1.x, ssq.x));
        ssq.y = fmaf(acc0.y, acc0.y, fmaf(acc1.y, acc1.y, ssq.y));
        ssq.z = fmaf(acc0.z, acc0.z, fmaf(acc1.z, acc1.z, ssq.z));
        ssq.w = fmaf(acc0.w, acc0.w, fmaf(acc1.w, acc1.w, ssq.w));
    }
    // lane l, comp q holds channel j=(4l+q)%6 : constant along lane stride 3
    float vals[8] = {ssum.x, ssum.y, ssum.z, ssum.w, ssq.x, ssq.y, ssq.z, ssq.w};
    #pragma unroll
    for (int q = 0; q < 8; q++) {
        vals[q] += __shfl_down(vals[q], 24, 64);
        vals[q] += __shfl_down(vals[q], 12, 64);
        vals[q] += __shfl_down(vals[q], 6, 64);
        vals[q] += __shfl_down(vals[q], 3, 64);
    }
    __shared__ float red[4][3][8];
    if (lane < 3) {
        #pragma unroll
        for (int q = 0; q < 8; q++) red[wv][lane][q] = vals[q];
    }
    __syncthreads();
    if (tid < 24) {
        int l0 = tid >> 3, qq = tid & 7;
        float v = red[0][l0][qq] + red[1][l0][qq] + red[2][l0][qq] + red[3][l0][qq];
        int j = (4 * l0 + (qq & 3)) % 6;
        atomicAdd(&stats_out[(qq < 4 ? 0 : 6) + j], v);
    }
}

// ---------- GEMM1: bf16 s_act (NC=50, 19.2KB LDS), bf16 partials; waves own 8 graphs ----------
__global__ __launch_bounds__(256) void gemm1_kernel(const unsigned short* __restrict__ agg3,
                                                    const float* __restrict__ stats,
                                                    const float* __restrict__ gam,
                                                    const float* __restrict__ bet,
                                                    const float* __restrict__ lw1,
                                                    unsigned int* __restrict__ partials, int NB) {
    __shared__ unsigned int s_act[NC * ROWF / 2];   // 4800 uints = 19.2KB (bf16 pairs)
    int tid = threadIdx.x;
    float inv = 1.f / (float)NB;
    float sa[6], sc[6];
    #pragma unroll
    for (int j = 0; j < 6; j++) {
        float mu = stats[j] * inv;
        float var = stats[6 + j] * inv - mu * mu;
        float rs = rsqrtf(var + BN_EPS);
        float a = gam[j] * rs;
        sa[j] = a; sc[j] = bet[j] - mu * a;
    }
    int n0 = blockIdx.x * NC;
    const unsigned int* ab = (const unsigned int*)(agg3 + (size_t)n0 * ROWF);
    for (int idx = tid; idx < NC * ROWF / 2; idx += 256) {
        unsigned int q = ab[idx];
        float v0 = __uint_as_float(q << 16);
        float v1 = __uint_as_float(q & 0xFFFF0000u);
        int j0 = (2 * idx) % 6;                   // even; j1 = j0+1
        float t0 = fmaf(sa[j0], v0, sc[j0]);
        float t1 = fmaf(sa[j0 + 1], v1, sc[j0 + 1]);
        t0 = t0 > 0.f ? t0 : 0.f;
        t1 = t1 > 0.f ? t1 : 0.f;
        s_act[idx] = bf16pack(t0, t1);
    }
    __syncthreads();
    int wv = tid >> 6, lane = tid & 63;
    int b0 = wv * 8;
    float4 acc[8];
    #pragma unroll
    for (int i = 0; i < 8; i++) acc[i] = make_float4(0.f, 0.f, 0.f, 0.f);
    const float* wbase = lw1 + (size_t)n0 * 6 * 256 + 4 * lane;
    for (int nl = 0; nl < NC; nl++) {
        float4 w6[6];
        #pragma unroll
        for (int j = 0; j < 6; j++)
            w6[j] = *(const float4*)(wbase + ((size_t)nl * 6 + j) * 256);
        const unsigned int* hu = &s_act[nl * (ROWF / 2) + b0 * 3];
        #pragma unroll
        for (int bb = 0; bb < 8; bb++) {
            unsigned int q0 = hu[bb * 3], q1 = hu[bb * 3 + 1], q2 = hu[bb * 3 + 2];
            float h0 = __uint_as_float(q0 << 16), h1 = __uint_as_float(q0 & 0xFFFF0000u);
            float h2 = __uint_as_float(q1 << 16), h3 = __uint_as_float(q1 & 0xFFFF0000u);
            float h4 = __uint_as_float(q2 << 16), h5 = __uint_as_float(q2 & 0xFFFF0000u);
            float4 a = acc[bb];
            a.x = fmaf(h0, w6[0].x, a.x); a.y = fmaf(h0, w6[0].y, a.y);
            a.z = fmaf(h0, w6[0].z, a.z); a.w = fmaf(h0, w6[0].w, a.w);
            a.x = fmaf(h1, w6[1].x, a.x); a.y = fmaf(h1, w6[1].y, a.y);
            a.z = fmaf(h1, w6[1].z, a.z); a.w = fmaf(h1, w6[1].w, a.w);
            a.x = fmaf(h2, w6[2].x, a.x); a.y = fmaf(h2, w6[2].y, a.y);
            a.z = fmaf(h2, w6[2].z, a.z); a.w = fmaf(h2, w6[2].w, a.w);
            a.x = fmaf(h3, w6[3].x, a.x); a.y = fmaf(h3, w6[3].y, a.y);
            a.z = fmaf(h3, w6[3].z, a.z); a.w = fmaf(h3, w6[3].w, a.w);
            a.x = fmaf(h4, w6[4].x, a.x); a.y = fmaf(h4, w6[4].y, a.y);
            a.z = fmaf(h4, w6[4].z, a.z); a.w = fmaf(h4, w6[4].w, a.w);
            a.x = fmaf(h5, w6[5].x, a.x); a.y = fmaf(h5, w6[5].y, a.y);
            a.z = fmaf(h5, w6[5].z, a.z); a.w = fmaf(h5, w6[5].w, a.w);
            acc[bb] = a;
        }
    }
    // write bf16 partials: row (split*32 + graph) of 256 bf16 = 128 uints; lane owns uints [2*lane, 2*lane+1]
    #pragma unroll
    for (int bb = 0; bb < 8; bb++) {
        unsigned int* prow = partials + (((size_t)blockIdx.x * BGR) + b0 + bb) * 128;
        *(uint2*)&prow[2 * lane] = make_uint2(bf16pack(acc[bb].x, acc[bb].y),
                                             bf16pack(acc[bb].z, acc[bb].w));
    }
}

// ---------- reduce bf16 partials[GSPLITS][32*128u] -> p2[RGROUPS][32*256] fp32 ----------
__global__ __launch_bounds__(256) void reduce1_kernel(const unsigned int* __restrict__ partials,
                                                      float* __restrict__ p2) {
    int o = blockIdx.x * 256 + threadIdx.x;   // uint index in [0, 4096); grid.x = 16
    int g = blockIdx.y;                        // 0..15
    float a0 = 0.f, a1 = 0.f;
    for (int s = g; s < GSPLITS; s += RGROUPS) {
        unsigned int q = partials[(size_t)s * (BGR * 128) + o];
        a0 += __uint_as_float(q << 16);
        a1 += __uint_as_float(q & 0xFFFF0000u);
    }
    p2[(size_t)g * (BGR * 256) + 2 * o]     = a0;
    p2[(size_t)g * (BGR * 256) + 2 * o + 1] = a1;
}

// ---------- tail: sum 16 groups + lb1/relu, then 256->128->64->32 ----------
__global__ __launch_bounds__(1024) void tail_kernel(const float* __restrict__ p2,
                                                    const float* __restrict__ lb1,
                                                    const float* __restrict__ lw2, const float* __restrict__ lb2,
                                                    const float* __restrict__ lw3, const float* __restrict__ lb3,
                                                    const float* __restrict__ lw4, const float* __restrict__ lb4,
                                                    float* __restrict__ out) {
    __shared__ float red[4][256];
    __shared__ float s1[256], s2[128], s3[64];
    int b = blockIdx.x;
    int tid = threadIdx.x;
    int c = tid & 255, sg = tid >> 8;
    float a = 0.f;
    for (int g = sg; g < RGROUPS; g += 4)
        a += p2[(size_t)g * (BGR * 256) + b * 256 + c];
    red[sg][c] = a;
    __syncthreads();
    if (tid < 256) {
        float v = red[0][tid] + red[1][tid] + red[2][tid] + red[3][tid] + lb1[tid];
        s1[tid] = v > 0.f ? v : 0.f;
    }
    __syncthreads();
    if (tid < 128) {
        float acc = lb2[tid];
        for (int k = 0; k < 256; k++) acc += s1[k] * lw2[k * 128 + tid];
        s2[tid] = acc > 0.f ? acc : 0.f;
    }
    __syncthreads();
    if (tid < 64) {
        float acc = lb3[tid];
        for (int k = 0; k < 128; k++) acc += s2[k] * lw3[k * 64 + tid];
        s3[tid] = acc > 0.f ? acc : 0.f;
    }
    __syncthreads();
    if (tid < 32) {
        float acc = lb4[tid];
        for (int k = 0; k < 64; k++) acc += s3[k] * lw4[k * 32 + tid];
        out[b * 32 + tid] = acc;
    }
}

extern "C" void kernel_launch(void* const* d_in, const int* in_sizes, int n_in,
                              void* d_out, int out_size, void* d_ws, size_t ws_size,
                              hipStream_t stream) {
    const float* x   = (const float*)d_in[0];
    const int* edge  = (const int*)d_in[1];
    const float* W1  = (const float*)d_in[2];
    const float* g1  = (const float*)d_in[4];
    const float* be1 = (const float*)d_in[5];
    const float* W2  = (const float*)d_in[6];
    const float* g2  = (const float*)d_in[8];
    const float* be2 = (const float*)d_in[9];
    const float* W3  = (const float*)d_in[10];
    const float* g3  = (const float*)d_in[12];
    const float* be3 = (const float*)d_in[13];
    const float* lw1 = (const float*)d_in[14];
    const float* lb1 = (const float*)d_in[15];
    const float* lw2 = (const float*)d_in[16];
    const float* lb2 = (const float*)d_in[17];
    const float* lw3 = (const float*)d_in[18];
    const float* lb3 = (const float*)d_in[19];
    const float* lw4 = (const float*)d_in[20];
    const float* lb4 = (const float*)d_in[21];

    const int E = in_sizes[1] / 2;
    const int N = NNODES;
    const int B = in_sizes[0] / (N * 3);
    const int NB = B * N;
    const int nblk = (N + 255) / 256;

    char* ws = (char*)d_ws;
    size_t rowShorts = (size_t)N * ROWF * sizeof(unsigned short);  // 19.2 MB per bf16 buffer
    unsigned short* aggbuf = (unsigned short*)ws;
    unsigned short* mbuf   = (unsigned short*)(ws + rowShorts);
    unsigned int* partials = (unsigned int*)(ws + 2 * rowShorts);  // 1000*32*128u = 16.4 MB
    char* p = ws + 2 * rowShorts + (size_t)GSPLITS * BGR * 128 * 4;
    float* dis    = (float*)p;  p += (size_t)N * 4;
    int*   deg    = (int*)p;    p += (size_t)N * 4;
    int*   offs   = (int*)p;    p += (size_t)(N + 1) * 4;
    int*   cursor = (int*)p;    p += (size_t)N * 4;
    int*   bsum   = (int*)p;    p += 256 * 4;
    int*   bbase  = (int*)p;    p += 256 * 4;
    int2*  csr_rw = (int2*)p;   p += (size_t)E * 8;
    float* stats  = (float*)p;  p += 48 * 4;
    float* p2     = (float*)p;  p += (size_t)RGROUPS * BGR * 256 * 4;
    float* stats1 = stats, *stats2 = stats + 16, *stats3 = stats + 32;

    const int T = 256;

    hipMemsetAsync(deg, 0, (size_t)N * 4, stream);
    hipMemsetAsync(stats, 0, 48 * 4, stream);
    count_deg_kernel<<<(E + T - 1) / T, T, 0, stream>>>(edge + E, E, deg);
    make_dis_kernel<<<(N + T - 1) / T, T, 0, stream>>>(deg, dis, N);
    scanA_kernel<<<nblk, T, 0, stream>>>(deg, bsum, N);
    scanB_kernel<<<1, T, 0, stream>>>(bsum, bbase, offs + N, nblk);
    scanC_kernel<<<nblk, T, 0, stream>>>(deg, bbase, offs, cursor, N);
    fill_csr_kernel<<<(E + T - 1) / T, T, 0, stream>>>(edge, edge + E, dis, cursor, csr_rw, E);

    // layer 1: m1 = x@W1 (bf16) ; agg1 = S m1 (bf16, exact stats)
    t1_kernel<<<(N + 63) / 64, T, 0, stream>>>(x, W1, mbuf, N);
    gather_kernel<<<GATHER_BLOCKS, T, 0, stream>>>(mbuf, offs, csr_rw, dis, aggbuf, stats1, N);
    // layer 2
    t23_kernel<<<(NB + T - 1) / T, T, 0, stream>>>(aggbuf, stats1, g1, be1, W2, mbuf, NB);
    gather_kernel<<<GATHER_BLOCKS, T, 0, stream>>>(mbuf, offs, csr_rw, dis, aggbuf, stats2, N);
    // layer 3
    t23_kernel<<<(NB + T - 1) / T, T, 0, stream>>>(aggbuf, stats2, g2, be2, W3, mbuf, NB);
    gather_kernel<<<GATHER_BLOCKS, T, 0, stream>>>(mbuf, offs, csr_rw, dis, aggbuf, stats3, N);

    // MLP head (bf16 agg3 + bf16 partials; p2/tail fp32)
    gemm1_kernel<<<GSPLITS, T, 0, stream>>>(aggbuf, stats3, g3, be3, lw1, partials, NB);
    reduce1_kernel<<<dim3(16, RGROUPS), T, 0, stream>>>(partials, p2);
    tail_kernel<<<B, 1024, 0, stream>>>(p2, lb1, lw2, lb2, lw3, lb3, lw4, lb4, (float*)d_out);
}

// Round 14
// 450.206 us; speedup vs baseline: 1.0852x; 1.0301x over previous
//
#include <hip/hip_runtime.h>

#define NNODES 50000
#define BGR 32
#define ROWF 192              // 32 graphs * 6 channels per node row
#define BN_EPS 1e-5f
#define NC 25                 // nodes per gemm1 block; fp32 s_act 19.2KB LDS -> 8 blocks/CU
#define GSPLITS (NNODES / NC) // 2000
#define RGROUPS 16
#define GATHER_BLOCKS 1024    // 2048 measured +143us (L2 thrash, r8); keep 1024

// bf16 helpers: m/agg/partials stored bf16; LDS + all math fp32 (r13: LDS bf16 unpack cost +25us)
__device__ inline unsigned int bf16rne(float x) {
    unsigned int u = __float_as_uint(x);
    return (u + 0x7FFFu + ((u >> 16) & 1u)) >> 16;
}
__device__ inline unsigned int bf16pack(float a, float b) {
    return bf16rne(a) | (bf16rne(b) << 16);
}
__device__ inline float4 ldrow_bf16(const unsigned short* p) {
    uint2 q = *(const uint2*)p;                 // 4 bf16 = 8B per lane
    float4 v;
    v.x = __uint_as_float(q.x << 16);
    v.y = __uint_as_float(q.x & 0xFFFF0000u);
    v.z = __uint_as_float(q.y << 16);
    v.w = __uint_as_float(q.y & 0xFFFF0000u);
    return v;
}

// ---------- degree / normalization ----------
__global__ void count_deg_kernel(const int* __restrict__ col, int E, int* __restrict__ deg) {
    int e = blockIdx.x * blockDim.x + threadIdx.x;
    if (e < E) atomicAdd(&deg[col[e]], 1);
}

__global__ void make_dis_kernel(const int* __restrict__ deg, float* __restrict__ dis, int N) {
    int n = blockIdx.x * blockDim.x + threadIdx.x;
    if (n < N) dis[n] = rsqrtf((float)(deg[n] + 1));   // +1 self loop
}

// ---------- 3-phase scan: deg -> offs (exclusive), cursor copy ----------
__global__ __launch_bounds__(256) void scanA_kernel(const int* __restrict__ deg, int* __restrict__ bsum, int N) {
    __shared__ int lds[256];
    int i = blockIdx.x * 256 + threadIdx.x;
    lds[threadIdx.x] = (i < N) ? deg[i] : 0;
    __syncthreads();
    for (int off = 128; off > 0; off >>= 1) {
        if (threadIdx.x < off) lds[threadIdx.x] += lds[threadIdx.x + off];
        __syncthreads();
    }
    if (threadIdx.x == 0) bsum[blockIdx.x] = lds[0];
}

__global__ __launch_bounds__(256) void scanB_kernel(const int* __restrict__ bsum, int* __restrict__ bbase,
                                                    int* __restrict__ offsN, int nblk) {
    __shared__ int lds[256];
    int t = threadIdx.x;
    int v = (t < nblk) ? bsum[t] : 0;
    lds[t] = v;
    __syncthreads();
    for (int off = 1; off < 256; off <<= 1) {
        int u = (t >= off) ? lds[t - off] : 0;
        __syncthreads();
        lds[t] += u;
        __syncthreads();
    }
    if (t < nblk) bbase[t] = lds[t] - v;   // exclusive base per block
    if (t == 255) offsN[0] = lds[255];     // total -> offs[N]
}

__global__ __launch_bounds__(256) void scanC_kernel(const int* __restrict__ deg, const int* __restrict__ bbase,
                                                    int* __restrict__ offs, int* __restrict__ cursor, int N) {
    __shared__ int lds[256];
    int i = blockIdx.x * 256 + threadIdx.x;
    int t = threadIdx.x;
    int v = (i < N) ? deg[i] : 0;
    lds[t] = v;
    __syncthreads();
    for (int off = 1; off < 256; off <<= 1) {
        int u = (t >= off) ? lds[t - off] : 0;
        __syncthreads();
        lds[t] += u;
        __syncthreads();
    }
    if (i < N) {
        int excl = bbase[blockIdx.x] + lds[t] - v;
        offs[i] = excl;
        cursor[i] = excl;
    }
}

// ---------- CSR fill: (src, weight) packed 8B per edge, grouped by dest ----------
__global__ void fill_csr_kernel(const int* __restrict__ row, const int* __restrict__ col,
                                const float* __restrict__ dis, int* __restrict__ cursor,
                                int2* __restrict__ csr_rw, int E) {
    int e = blockIdx.x * blockDim.x + threadIdx.x;
    if (e >= E) return;
    int r = row[e], c = col[e];
    int pos = atomicAdd(&cursor[c], 1);
    csr_rw[pos] = make_int2(r, __float_as_int(dis[r] * dis[c]));
}

// ---------- T1: x [B][N][3] -> m1 [N][32*6] node-major bf16, m1 = x @ W1 ----------
__global__ __launch_bounds__(256) void t1_kernel(const float* __restrict__ x,
                                                 const float* __restrict__ W,
                                                 unsigned short* __restrict__ m, int N) {
    __shared__ float xt[BGR][ROWF];   // 64 nodes * 3 floats per graph = 24KB
    __shared__ float sW[18];
    int tid = threadIdx.x;
    if (tid < 18) sW[tid] = W[tid];
    int n0 = blockIdx.x * 64;
    int nval = N - n0; if (nval > 64) nval = 64;
    int lim = nval * 3;
    for (int b = 0; b < BGR; b++) {
        if (tid < lim) xt[b][tid] = x[((size_t)b * N + n0) * 3 + tid];
    }
    __syncthreads();
    for (int i = 0; i < 8; i++) {
        int pi = i * 256 + tid;
        int nl = pi >> 5, b = pi & 31;
        if (nl < nval) {
            float h0 = xt[b][nl * 3], h1 = xt[b][nl * 3 + 1], h2 = xt[b][nl * 3 + 2];
            float o[6];
            #pragma unroll
            for (int j = 0; j < 6; j++)
                o[j] = h0 * sW[j] + h1 * sW[6 + j] + h2 * sW[12 + j];
            unsigned int* mp = (unsigned int*)(m + (size_t)(n0 + nl) * ROWF + b * 6);
            mp[0] = bf16pack(o[0], o[1]);
            mp[1] = bf16pack(o[2], o[3]);
            mp[2] = bf16pack(o[4], o[5]);
        }
    }
}

// ---------- T2/T3: m(bf16) = relu(bn(agg bf16, exact stats)) @ W ----------
__global__ __launch_bounds__(256) void t23_kernel(const unsigned short* __restrict__ agg,
                                                  const float* __restrict__ stats,
                                                  const float* __restrict__ gam,
                                                  const float* __restrict__ bet,
                                                  const float* __restrict__ W,
                                                  unsigned short* __restrict__ m, int NB) {
    __shared__ float sW[36];
    int tid = threadIdx.x;
    if (tid < 36) sW[tid] = W[tid];
    __syncthreads();
    float inv = 1.f / (float)NB;
    float sa[6], sc[6];
    #pragma unroll
    for (int j = 0; j < 6; j++) {
        float mu = stats[j] * inv;
        float var = stats[6 + j] * inv - mu * mu;
        float rs = rsqrtf(var + BN_EPS);
        float a = gam[j] * rs;
        sa[j] = a; sc[j] = bet[j] - mu * a;
    }
    size_t i = (size_t)blockIdx.x * 256 + tid;   // (n,b) pair; 6 bf16 = 12B, 4-aligned
    if (i >= (size_t)NB) return;
    const unsigned int* ap = (const unsigned int*)(agg + i * 6);
    unsigned int q0 = ap[0], q1 = ap[1], q2 = ap[2];
    float h[6];
    h[0] = __uint_as_float(q0 << 16); h[1] = __uint_as_float(q0 & 0xFFFF0000u);
    h[2] = __uint_as_float(q1 << 16); h[3] = __uint_as_float(q1 & 0xFFFF0000u);
    h[4] = __uint_as_float(q2 << 16); h[5] = __uint_as_float(q2 & 0xFFFF0000u);
    #pragma unroll
    for (int k = 0; k < 6; k++) {
        float v = fmaf(sa[k], h[k], sc[k]);
        h[k] = v > 0.f ? v : 0.f;
    }
    float o[6];
    #pragma unroll
    for (int j = 0; j < 6; j++) {
        float t = 0.f;
        #pragma unroll
        for (int k = 0; k < 6; k++) t = fmaf(h[k], sW[k * 6 + j], t);
        o[j] = t;
    }
    unsigned int* mp = (unsigned int*)(m + i * 6);
    mp[0] = bf16pack(o[0], o[1]);
    mp[1] = bf16pack(o[2], o[3]);
    mp[2] = bf16pack(o[4], o[5]);
}

// ---------- gather: wave handles TWO nodes (ILP x2); bf16 rows in AND out; fused exact BN stats ----------
__global__ __launch_bounds__(256) void gather_kernel(const unsigned short* __restrict__ m,
                                                     const int* __restrict__ offs,
                                                     const int2* __restrict__ csr_rw,
                                                     const float* __restrict__ dis,
                                                     unsigned short* __restrict__ agg,
                                                     float* __restrict__ stats_out, int N) {
    int tid = threadIdx.x;
    int wv = tid >> 6, lane = tid & 63;
    bool lact = lane < 48;                       // 48 lanes x 4 ch = 192 channels
    int loff = lane * 4;
    float4 ssum = make_float4(0.f, 0.f, 0.f, 0.f);
    float4 ssq  = make_float4(0.f, 0.f, 0.f, 0.f);
    int ngrp = (N + 7) >> 3;                     // 8 nodes per group (4 waves x 2)
    for (int grp = blockIdx.x; grp < ngrp; grp += gridDim.x) {
        int n0 = grp * 8 + wv;
        int n1 = n0 + 4;
        if (n0 >= N) continue;
        bool v1 = (n1 < N);
        float d0 = dis[n0];
        float d1 = v1 ? dis[n1] : 0.f;
        int s0 = offs[n0], e0 = offs[n0 + 1];
        int s1 = v1 ? offs[n1] : 0, e1 = v1 ? offs[n1 + 1] : 0;
        float4 acc0 = make_float4(0.f, 0.f, 0.f, 0.f);
        float4 acc1 = make_float4(0.f, 0.f, 0.f, 0.f);
        if (lact) {
            const float4 va = ldrow_bf16(m + (size_t)n0 * ROWF + loff);
            const float4 vb = ldrow_bf16(m + (size_t)(v1 ? n1 : n0) * ROWF + loff);
            float wa = d0 * d0, wb = d1 * d1;
            acc0.x = wa * va.x; acc0.y = wa * va.y; acc0.z = wa * va.z; acc0.w = wa * va.w;
            acc1.x = wb * vb.x; acc1.y = wb * vb.y; acc1.z = wb * vb.z; acc1.w = wb * vb.w;
        }
        int p0 = s0, p1 = s1;
        int len0 = e0 - s0, len1 = e1 - s1;
        int iters = len0 > len1 ? len0 : len1;
        for (int it = 0; it < iters; it++) {
            int  r0 = n0; float w0 = 0.f;
            int  r1 = v1 ? n1 : n0; float w1 = 0.f;
            if (p0 < e0) { int2 t0 = csr_rw[p0]; r0 = t0.x; w0 = __int_as_float(t0.y); }
            if (p1 < e1) { int2 t1 = csr_rw[p1]; r1 = t1.x; w1 = __int_as_float(t1.y); }
            if (lact) {
                const float4 va = ldrow_bf16(m + (size_t)r0 * ROWF + loff);
                const float4 vb = ldrow_bf16(m + (size_t)r1 * ROWF + loff);
                acc0.x = fmaf(w0, va.x, acc0.x); acc0.y = fmaf(w0, va.y, acc0.y);
                acc0.z = fmaf(w0, va.z, acc0.z); acc0.w = fmaf(w0, va.w, acc0.w);
                acc1.x = fmaf(w1, vb.x, acc1.x); acc1.y = fmaf(w1, vb.y, acc1.y);
                acc1.z = fmaf(w1, vb.z, acc1.z); acc1.w = fmaf(w1, vb.w, acc1.w);
            }
            p0++; p1++;
        }
        if (lact) {
            *(uint2*)(agg + (size_t)n0 * ROWF + loff) =
                make_uint2(bf16pack(acc0.x, acc0.y), bf16pack(acc0.z, acc0.w));
            if (v1)
                *(uint2*)(agg + (size_t)n1 * ROWF + loff) =
                    make_uint2(bf16pack(acc1.x, acc1.y), bf16pack(acc1.z, acc1.w));
        }
        ssum.x += acc0.x + acc1.x; ssum.y += acc0.y + acc1.y;
        ssum.z += acc0.z + acc1.z; ssum.w += acc0.w + acc1.w;
        ssq.x = fmaf(acc0.x, acc0.x, fmaf(acc1.x, acc1.x, ssq.x));
        ssq.y = fmaf(acc0.y, acc0.y, fmaf(acc1.y, acc1.y, ssq.y));
        ssq.z = fmaf(acc0.z, acc0.z, fmaf(acc1.z, acc1.z, ssq.z));
        ssq.w = fmaf(acc0.w, acc0.w, fmaf(acc1.w, acc1.w, ssq.w));
    }
    // lane l, comp q holds channel j=(4l+q)%6 : constant along lane stride 3
    float vals[8] = {ssum.x, ssum.y, ssum.z, ssum.w, ssq.x, ssq.y, ssq.z, ssq.w};
    #pragma unroll
    for (int q = 0; q < 8; q++) {
        vals[q] += __shfl_down(vals[q], 24, 64);
        vals[q] += __shfl_down(vals[q], 12, 64);
        vals[q] += __shfl_down(vals[q], 6, 64);
        vals[q] += __shfl_down(vals[q], 3, 64);
    }
    __shared__ float red[4][3][8];
    if (lane < 3) {
        #pragma unroll
        for (int q = 0; q < 8; q++) red[wv][lane][q] = vals[q];
    }
    __syncthreads();
    if (tid < 24) {
        int l0 = tid >> 3, qq = tid & 7;
        float v = red[0][l0][qq] + red[1][l0][qq] + red[2][l0][qq] + red[3][l0][qq];
        int j = (4 * l0 + (qq & 3)) % 6;
        atomicAdd(&stats_out[(qq < 4 ? 0 : 6) + j], v);
    }
}

// ---------- GEMM1 v3: fp32 s_act (NC=25, 19.2KB LDS -> 8 blocks/CU), bf16 partials epilogue ----------
__global__ __launch_bounds__(256) void gemm1_kernel(const unsigned short* __restrict__ agg3,
                                                    const float* __restrict__ stats,
                                                    const float* __restrict__ gam,
                                                    const float* __restrict__ bet,
                                                    const float* __restrict__ lw1,
                                                    unsigned int* __restrict__ partials, int NB) {
    __shared__ float s_act[NC * ROWF];   // 4800 floats = 19.2KB
    int tid = threadIdx.x;
    float inv = 1.f / (float)NB;
    float sa[6], sc[6];
    #pragma unroll
    for (int j = 0; j < 6; j++) {
        float mu = stats[j] * inv;
        float var = stats[6 + j] * inv - mu * mu;
        float rs = rsqrtf(var + BN_EPS);
        float a = gam[j] * rs;
        sa[j] = a; sc[j] = bet[j] - mu * a;
    }
    int n0 = blockIdx.x * NC;
    const unsigned int* ab = (const unsigned int*)(agg3 + (size_t)n0 * ROWF);
    for (int idx = tid; idx < NC * ROWF / 2; idx += 256) {
        unsigned int q = ab[idx];
        float v0 = __uint_as_float(q << 16);
        float v1 = __uint_as_float(q & 0xFFFF0000u);
        int j0 = (2 * idx) % 6;                   // even; j1 = j0+1
        float t0 = fmaf(sa[j0], v0, sc[j0]);
        float t1 = fmaf(sa[j0 + 1], v1, sc[j0 + 1]);
        s_act[2 * idx]     = t0 > 0.f ? t0 : 0.f;
        s_act[2 * idx + 1] = t1 > 0.f ? t1 : 0.f;
    }
    __syncthreads();
    int wv = tid >> 6, lane = tid & 63;
    int b0 = wv * 8;
    float4 acc[8];
    #pragma unroll
    for (int i = 0; i < 8; i++) acc[i] = make_float4(0.f, 0.f, 0.f, 0.f);
    const float* wbase = lw1 + (size_t)n0 * 6 * 256 + 4 * lane;
    for (int nl = 0; nl < NC; nl++) {
        float4 w6[6];
        #pragma unroll
        for (int j = 0; j < 6; j++)
            w6[j] = *(const float4*)(wbase + ((size_t)nl * 6 + j) * 256);
        const float* hb = &s_act[nl * ROWF + b0 * 6];
        #pragma unroll
        for (int bb = 0; bb < 8; bb++) {
            const float* hp = hb + bb * 6;
            float2 h01 = *(const float2*)hp;
            float2 h23 = *(const float2*)(hp + 2);
            float2 h45 = *(const float2*)(hp + 4);
            float4 a = acc[bb];
            a.x = fmaf(h01.x, w6[0].x, a.x); a.y = fmaf(h01.x, w6[0].y, a.y);
            a.z = fmaf(h01.x, w6[0].z, a.z); a.w = fmaf(h01.x, w6[0].w, a.w);
            a.x = fmaf(h01.y, w6[1].x, a.x); a.y = fmaf(h01.y, w6[1].y, a.y);
            a.z = fmaf(h01.y, w6[1].z, a.z); a.w = fmaf(h01.y, w6[1].w, a.w);
            a.x = fmaf(h23.x, w6[2].x, a.x); a.y = fmaf(h23.x, w6[2].y, a.y);
            a.z = fmaf(h23.x, w6[2].z, a.z); a.w = fmaf(h23.x, w6[2].w, a.w);
            a.x = fmaf(h23.y, w6[3].x, a.x); a.y = fmaf(h23.y, w6[3].y, a.y);
            a.z = fmaf(h23.y, w6[3].z, a.z); a.w = fmaf(h23.y, w6[3].w, a.w);
            a.x = fmaf(h45.x, w6[4].x, a.x); a.y = fmaf(h45.x, w6[4].y, a.y);
            a.z = fmaf(h45.x, w6[4].z, a.z); a.w = fmaf(h45.x, w6[4].w, a.w);
            a.x = fmaf(h45.y, w6[5].x, a.x); a.y = fmaf(h45.y, w6[5].y, a.y);
            a.z = fmaf(h45.y, w6[5].z, a.z); a.w = fmaf(h45.y, w6[5].w, a.w);
            acc[bb] = a;
        }
    }
    // epilogue-only bf16 pack: row (split*32 + graph) of 256 bf16 = 128 uints
    #pragma unroll
    for (int bb = 0; bb < 8; bb++) {
        unsigned int* prow = partials + (((size_t)blockIdx.x * BGR) + b0 + bb) * 128;
        *(uint2*)&prow[2 * lane] = make_uint2(bf16pack(acc[bb].x, acc[bb].y),
                                             bf16pack(acc[bb].z, acc[bb].w));
    }
}

// ---------- reduce bf16 partials[GSPLITS][32*128u] -> p2[RGROUPS][32*256] fp32 ----------
__global__ __launch_bounds__(256) void reduce1_kernel(const unsigned int* __restrict__ partials,
                                                      float* __restrict__ p2) {
    int o = blockIdx.x * 256 + threadIdx.x;   // uint index in [0, 4096); grid.x = 16
    int g = blockIdx.y;                        // 0..15
    float a0 = 0.f, a1 = 0.f;
    for (int s = g; s < GSPLITS; s += RGROUPS) {
        unsigned int q = partials[(size_t)s * (BGR * 128) + o];
        a0 += __uint_as_float(q << 16);
        a1 += __uint_as_float(q & 0xFFFF0000u);
    }
    p2[(size_t)g * (BGR * 256) + 2 * o]     = a0;
    p2[(size_t)g * (BGR * 256) + 2 * o + 1] = a1;
}

// ---------- tail: sum 16 groups + lb1/relu, then 256->128->64->32 ----------
__global__ __launch_bounds__(1024) void tail_kernel(const float* __restrict__ p2,
                                                    const float* __restrict__ lb1,
                                                    const float* __restrict__ lw2, const float* __restrict__ lb2,
                                                    const float* __restrict__ lw3, const float* __restrict__ lb3,
                                                    const float* __restrict__ lw4, const float* __restrict__ lb4,
                                                    float* __restrict__ out) {
    __shared__ float red[4][256];
    __shared__ float s1[256], s2[128], s3[64];
    int b = blockIdx.x;
    int tid = threadIdx.x;
    int c = tid & 255, sg = tid >> 8;
    float a = 0.f;
    for (int g = sg; g < RGROUPS; g += 4)
        a += p2[(size_t)g * (BGR * 256) + b * 256 + c];
    red[sg][c] = a;
    __syncthreads();
    if (tid < 256) {
        float v = red[0][tid] + red[1][tid] + red[2][tid] + red[3][tid] + lb1[tid];
        s1[tid] = v > 0.f ? v : 0.f;
    }
    __syncthreads();
    if (tid < 128) {
        float acc = lb2[tid];
        for (int k = 0; k < 256; k++) acc += s1[k] * lw2[k * 128 + tid];
        s2[tid] = acc > 0.f ? acc : 0.f;
    }
    __syncthreads();
    if (tid < 64) {
        float acc = lb3[tid];
        for (int k = 0; k < 128; k++) acc += s2[k] * lw3[k * 64 + tid];
        s3[tid] = acc > 0.f ? acc : 0.f;
    }
    __syncthreads();
    if (tid < 32) {
        float acc = lb4[tid];
        for (int k = 0; k < 64; k++) acc += s3[k] * lw4[k * 32 + tid];
        out[b * 32 + tid] = acc;
    }
}

extern "C" void kernel_launch(void* const* d_in, const int* in_sizes, int n_in,
                              void* d_out, int out_size, void* d_ws, size_t ws_size,
                              hipStream_t stream) {
    const float* x   = (const float*)d_in[0];
    const int* edge  = (const int*)d_in[1];
    const float* W1  = (const float*)d_in[2];
    const float* g1  = (const float*)d_in[4];
    const float* be1 = (const float*)d_in[5];
    const float* W2  = (const float*)d_in[6];
    const float* g2  = (const float*)d_in[8];
    const float* be2 = (const float*)d_in[9];
    const float* W3  = (const float*)d_in[10];
    const float* g3  = (const float*)d_in[12];
    const float* be3 = (const float*)d_in[13];
    const float* lw1 = (const float*)d_in[14];
    const float* lb1 = (const float*)d_in[15];
    const float* lw2 = (const float*)d_in[16];
    const float* lb2 = (const float*)d_in[17];
    const float* lw3 = (const float*)d_in[18];
    const float* lb3 = (const float*)d_in[19];
    const float* lw4 = (const float*)d_in[20];
    const float* lb4 = (const float*)d_in[21];

    const int E = in_sizes[1] / 2;
    const int N = NNODES;
    const int B = in_sizes[0] / (N * 3);
    const int NB = B * N;
    const int nblk = (N + 255) / 256;

    char* ws = (char*)d_ws;
    size_t rowShorts = (size_t)N * ROWF * sizeof(unsigned short);  // 19.2 MB per bf16 buffer
    unsigned short* aggbuf = (unsigned short*)ws;
    unsigned short* mbuf   = (unsigned short*)(ws + rowShorts);
    unsigned int* partials = (unsigned int*)(ws + 2 * rowShorts);  // 2000*32*128u = 32.8 MB
    char* p = ws + 2 * rowShorts + (size_t)GSPLITS * BGR * 128 * 4;
    float* dis    = (float*)p;  p += (size_t)N * 4;
    int*   deg    = (int*)p;    p += (size_t)N * 4;
    int*   offs   = (int*)p;    p += (size_t)(N + 1) * 4;
    int*   cursor = (int*)p;    p += (size_t)N * 4;
    int*   bsum   = (int*)p;    p += 256 * 4;
    int*   bbase  = (int*)p;    p += 256 * 4;
    int2*  csr_rw = (int2*)p;   p += (size_t)E * 8;
    float* stats  = (float*)p;  p += 48 * 4;
    float* p2     = (float*)p;  p += (size_t)RGROUPS * BGR * 256 * 4;
    float* stats1 = stats, *stats2 = stats + 16, *stats3 = stats + 32;

    const int T = 256;

    hipMemsetAsync(deg, 0, (size_t)N * 4, stream);
    hipMemsetAsync(stats, 0, 48 * 4, stream);
    count_deg_kernel<<<(E + T - 1) / T, T, 0, stream>>>(edge + E, E, deg);
    make_dis_kernel<<<(N + T - 1) / T, T, 0, stream>>>(deg, dis, N);
    scanA_kernel<<<nblk, T, 0, stream>>>(deg, bsum, N);
    scanB_kernel<<<1, T, 0, stream>>>(bsum, bbase, offs + N, nblk);
    scanC_kernel<<<nblk, T, 0, stream>>>(deg, bbase, offs, cursor, N);
    fill_csr_kernel<<<(E + T - 1) / T, T, 0, stream>>>(edge, edge + E, dis, cursor, csr_rw, E);

    // layer 1: m1 = x@W1 (bf16) ; agg1 = S m1 (bf16, exact stats)
    t1_kernel<<<(N + 63) / 64, T, 0, stream>>>(x, W1, mbuf, N);
    gather_kernel<<<GATHER_BLOCKS, T, 0, stream>>>(mbuf, offs, csr_rw, dis, aggbuf, stats1, N);
    // layer 2
    t23_kernel<<<(NB + T - 1) / T, T, 0, stream>>>(aggbuf, stats1, g1, be1, W2, mbuf, NB);
    gather_kernel<<<GATHER_BLOCKS, T, 0, stream>>>(mbuf, offs, csr_rw, dis, aggbuf, stats2, N);
    // layer 3
    t23_kernel<<<(NB + T - 1) / T, T, 0, stream>>>(aggbuf, stats2, g2, be2, W3, mbuf, NB);
    gather_kernel<<<GATHER_BLOCKS, T, 0, stream>>>(mbuf, offs, csr_rw, dis, aggbuf, stats3, N);

    // MLP head (bf16 agg3 in, fp32 LDS/math, bf16 partials out; p2/tail fp32)
    gemm1_kernel<<<GSPLITS, T, 0, stream>>>(aggbuf, stats3, g3, be3, lw1, partials, NB);
    reduce1_kernel<<<dim3(16, RGROUPS), T, 0, stream>>>(partials, p2);
    tail_kernel<<<B, 1024, 0, stream>>>(p2, lb1, lw2, lb2, lw3, lb3, lw4, lb4, (float*)d_out);
}

// Round 15
// 435.170 us; speedup vs baseline: 1.1227x; 1.0346x over previous
//
#include <hip/hip_runtime.h>

#define NNODES 50000
#define BGR 32
#define ROWF 192              // 32 graphs * 6 channels per node row
#define BN_EPS 1e-5f
#define NC 50                 // nodes per gemm1 block; 25 (+12us, r14) and 100 (+50us, r12) both worse
#define GSPLITS (NNODES / NC) // 1000
#define RGROUPS 16
#define GATHER_BLOCKS 1024    // 2048 measured +143us (L2 thrash, r8); keep 1024

// bf16 helpers: m/agg/partials stored bf16; LDS + all math fp32 (r13: LDS bf16 unpack cost +25us)
__device__ inline unsigned int bf16rne(float x) {
    unsigned int u = __float_as_uint(x);
    return (u + 0x7FFFu + ((u >> 16) & 1u)) >> 16;
}
__device__ inline unsigned int bf16pack(float a, float b) {
    return bf16rne(a) | (bf16rne(b) << 16);
}
__device__ inline float4 ldrow_bf16(const unsigned short* p) {
    uint2 q = *(const uint2*)p;                 // 4 bf16 = 8B per lane
    float4 v;
    v.x = __uint_as_float(q.x << 16);
    v.y = __uint_as_float(q.x & 0xFFFF0000u);
    v.z = __uint_as_float(q.y << 16);
    v.w = __uint_as_float(q.y & 0xFFFF0000u);
    return v;
}

// ---------- degree / normalization ----------
__global__ void count_deg_kernel(const int* __restrict__ col, int E, int* __restrict__ deg) {
    int e = blockIdx.x * blockDim.x + threadIdx.x;
    if (e < E) atomicAdd(&deg[col[e]], 1);
}

__global__ void make_dis_kernel(const int* __restrict__ deg, float* __restrict__ dis, int N) {
    int n = blockIdx.x * blockDim.x + threadIdx.x;
    if (n < N) dis[n] = rsqrtf((float)(deg[n] + 1));   // +1 self loop
}

// ---------- 3-phase scan: deg -> offs (exclusive), cursor copy ----------
__global__ __launch_bounds__(256) void scanA_kernel(const int* __restrict__ deg, int* __restrict__ bsum, int N) {
    __shared__ int lds[256];
    int i = blockIdx.x * 256 + threadIdx.x;
    lds[threadIdx.x] = (i < N) ? deg[i] : 0;
    __syncthreads();
    for (int off = 128; off > 0; off >>= 1) {
        if (threadIdx.x < off) lds[threadIdx.x] += lds[threadIdx.x + off];
        __syncthreads();
    }
    if (threadIdx.x == 0) bsum[blockIdx.x] = lds[0];
}

__global__ __launch_bounds__(256) void scanB_kernel(const int* __restrict__ bsum, int* __restrict__ bbase,
                                                    int* __restrict__ offsN, int nblk) {
    __shared__ int lds[256];
    int t = threadIdx.x;
    int v = (t < nblk) ? bsum[t] : 0;
    lds[t] = v;
    __syncthreads();
    for (int off = 1; off < 256; off <<= 1) {
        int u = (t >= off) ? lds[t - off] : 0;
        __syncthreads();
        lds[t] += u;
        __syncthreads();
    }
    if (t < nblk) bbase[t] = lds[t] - v;   // exclusive base per block
    if (t == 255) offsN[0] = lds[255];     // total -> offs[N]
}

__global__ __launch_bounds__(256) void scanC_kernel(const int* __restrict__ deg, const int* __restrict__ bbase,
                                                    int* __restrict__ offs, int* __restrict__ cursor, int N) {
    __shared__ int lds[256];
    int i = blockIdx.x * 256 + threadIdx.x;
    int t = threadIdx.x;
    int v = (i < N) ? deg[i] : 0;
    lds[t] = v;
    __syncthreads();
    for (int off = 1; off < 256; off <<= 1) {
        int u = (t >= off) ? lds[t - off] : 0;
        __syncthreads();
        lds[t] += u;
        __syncthreads();
    }
    if (i < N) {
        int excl = bbase[blockIdx.x] + lds[t] - v;
        offs[i] = excl;
        cursor[i] = excl;
    }
}

// ---------- CSR fill: (src, weight) packed 8B per edge, grouped by dest ----------
__global__ void fill_csr_kernel(const int* __restrict__ row, const int* __restrict__ col,
                                const float* __restrict__ dis, int* __restrict__ cursor,
                                int2* __restrict__ csr_rw, int E) {
    int e = blockIdx.x * blockDim.x + threadIdx.x;
    if (e >= E) return;
    int r = row[e], c = col[e];
    int pos = atomicAdd(&cursor[c], 1);
    csr_rw[pos] = make_int2(r, __float_as_int(dis[r] * dis[c]));
}

// ---------- T1: x [B][N][3] -> m1 [N][32*6] node-major bf16, m1 = x @ W1 ----------
__global__ __launch_bounds__(256) void t1_kernel(const float* __restrict__ x,
                                                 const float* __restrict__ W,
                                                 unsigned short* __restrict__ m, int N) {
    __shared__ float xt[BGR][ROWF];   // 64 nodes * 3 floats per graph = 24KB
    __shared__ float sW[18];
    int tid = threadIdx.x;
    if (tid < 18) sW[tid] = W[tid];
    int n0 = blockIdx.x * 64;
    int nval = N - n0; if (nval > 64) nval = 64;
    int lim = nval * 3;
    for (int b = 0; b < BGR; b++) {
        if (tid < lim) xt[b][tid] = x[((size_t)b * N + n0) * 3 + tid];
    }
    __syncthreads();
    for (int i = 0; i < 8; i++) {
        int pi = i * 256 + tid;
        int nl = pi >> 5, b = pi & 31;
        if (nl < nval) {
            float h0 = xt[b][nl * 3], h1 = xt[b][nl * 3 + 1], h2 = xt[b][nl * 3 + 2];
            float o[6];
            #pragma unroll
            for (int j = 0; j < 6; j++)
                o[j] = h0 * sW[j] + h1 * sW[6 + j] + h2 * sW[12 + j];
            unsigned int* mp = (unsigned int*)(m + (size_t)(n0 + nl) * ROWF + b * 6);
            mp[0] = bf16pack(o[0], o[1]);
            mp[1] = bf16pack(o[2], o[3]);
            mp[2] = bf16pack(o[4], o[5]);
        }
    }
}

// ---------- T2/T3: m(bf16) = relu(bn(agg bf16, exact stats)) @ W ----------
__global__ __launch_bounds__(256) void t23_kernel(const unsigned short* __restrict__ agg,
                                                  const float* __restrict__ stats,
                                                  const float* __restrict__ gam,
                                                  const float* __restrict__ bet,
                                                  const float* __restrict__ W,
                                                  unsigned short* __restrict__ m, int NB) {
    __shared__ float sW[36];
    int tid = threadIdx.x;
    if (tid < 36) sW[tid] = W[tid];
    __syncthreads();
    float inv = 1.f / (float)NB;
    float sa[6], sc[6];
    #pragma unroll
    for (int j = 0; j < 6; j++) {
        float mu = stats[j] * inv;
        float var = stats[6 + j] * inv - mu * mu;
        float rs = rsqrtf(var + BN_EPS);
        float a = gam[j] * rs;
        sa[j] = a; sc[j] = bet[j] - mu * a;
    }
    size_t i = (size_t)blockIdx.x * 256 + tid;   // (n,b) pair; 6 bf16 = 12B, 4-aligned
    if (i >= (size_t)NB) return;
    const unsigned int* ap = (const unsigned int*)(agg + i * 6);
    unsigned int q0 = ap[0], q1 = ap[1], q2 = ap[2];
    float h[6];
    h[0] = __uint_as_float(q0 << 16); h[1] = __uint_as_float(q0 & 0xFFFF0000u);
    h[2] = __uint_as_float(q1 << 16); h[3] = __uint_as_float(q1 & 0xFFFF0000u);
    h[4] = __uint_as_float(q2 << 16); h[5] = __uint_as_float(q2 & 0xFFFF0000u);
    #pragma unroll
    for (int k = 0; k < 6; k++) {
        float v = fmaf(sa[k], h[k], sc[k]);
        h[k] = v > 0.f ? v : 0.f;
    }
    float o[6];
    #pragma unroll
    for (int j = 0; j < 6; j++) {
        float t = 0.f;
        #pragma unroll
        for (int k = 0; k < 6; k++) t = fmaf(h[k], sW[k * 6 + j], t);
        o[j] = t;
    }
    unsigned int* mp = (unsigned int*)(m + i * 6);
    mp[0] = bf16pack(o[0], o[1]);
    mp[1] = bf16pack(o[2], o[3]);
    mp[2] = bf16pack(o[4], o[5]);
}

// ---------- gather: wave handles TWO nodes (ILP x2); bf16 rows in AND out; fused exact BN stats ----------
__global__ __launch_bounds__(256) void gather_kernel(const unsigned short* __restrict__ m,
                                                     const int* __restrict__ offs,
                                                     const int2* __restrict__ csr_rw,
                                                     const float* __restrict__ dis,
                                                     unsigned short* __restrict__ agg,
                                                     float* __restrict__ stats_out, int N) {
    int tid = threadIdx.x;
    int wv = tid >> 6, lane = tid & 63;
    bool lact = lane < 48;                       // 48 lanes x 4 ch = 192 channels
    int loff = lane * 4;
    float4 ssum = make_float4(0.f, 0.f, 0.f, 0.f);
    float4 ssq  = make_float4(0.f, 0.f, 0.f, 0.f);
    int ngrp = (N + 7) >> 3;                     // 8 nodes per group (4 waves x 2)
    for (int grp = blockIdx.x; grp < ngrp; grp += gridDim.x) {
        int n0 = grp * 8 + wv;
        int n1 = n0 + 4;
        if (n0 >= N) continue;
        bool v1 = (n1 < N);
        float d0 = dis[n0];
        float d1 = v1 ? dis[n1] : 0.f;
        int s0 = offs[n0], e0 = offs[n0 + 1];
        int s1 = v1 ? offs[n1] : 0, e1 = v1 ? offs[n1 + 1] : 0;
        float4 acc0 = make_float4(0.f, 0.f, 0.f, 0.f);
        float4 acc1 = make_float4(0.f, 0.f, 0.f, 0.f);
        if (lact) {
            const float4 va = ldrow_bf16(m + (size_t)n0 * ROWF + loff);
            const float4 vb = ldrow_bf16(m + (size_t)(v1 ? n1 : n0) * ROWF + loff);
            float wa = d0 * d0, wb = d1 * d1;
            acc0.x = wa * va.x; acc0.y = wa * va.y; acc0.z = wa * va.z; acc0.w = wa * va.w;
            acc1.x = wb * vb.x; acc1.y = wb * vb.y; acc1.z = wb * vb.z; acc1.w = wb * vb.w;
        }
        int p0 = s0, p1 = s1;
        int len0 = e0 - s0, len1 = e1 - s1;
        int iters = len0 > len1 ? len0 : len1;
        for (int it = 0; it < iters; it++) {
            int  r0 = n0; float w0 = 0.f;
            int  r1 = v1 ? n1 : n0; float w1 = 0.f;
            if (p0 < e0) { int2 t0 = csr_rw[p0]; r0 = t0.x; w0 = __int_as_float(t0.y); }
            if (p1 < e1) { int2 t1 = csr_rw[p1]; r1 = t1.x; w1 = __int_as_float(t1.y); }
            if (lact) {
                const float4 va = ldrow_bf16(m + (size_t)r0 * ROWF + loff);
                const float4 vb = ldrow_bf16(m + (size_t)r1 * ROWF + loff);
                acc0.x = fmaf(w0, va.x, acc0.x); acc0.y = fmaf(w0, va.y, acc0.y);
                acc0.z = fmaf(w0, va.z, acc0.z); acc0.w = fmaf(w0, va.w, acc0.w);
                acc1.x = fmaf(w1, vb.x, acc1.x); acc1.y = fmaf(w1, vb.y, acc1.y);
                acc1.z = fmaf(w1, vb.z, acc1.z); acc1.w = fmaf(w1, vb.w, acc1.w);
            }
            p0++; p1++;
        }
        if (lact) {
            *(uint2*)(agg + (size_t)n0 * ROWF + loff) =
                make_uint2(bf16pack(acc0.x, acc0.y), bf16pack(acc0.z, acc0.w));
            if (v1)
                *(uint2*)(agg + (size_t)n1 * ROWF + loff) =
                    make_uint2(bf16pack(acc1.x, acc1.y), bf16pack(acc1.z, acc1.w));
        }
        ssum.x += acc0.x + acc1.x; ssum.y += acc0.y + acc1.y;
        ssum.z += acc0.z + acc1.z; ssum.w += acc0.w + acc1.w;
        ssq.x = fmaf(acc0.x, acc0.x, fmaf(acc1.x, acc1.x, ssq.x));
        ssq.y = fmaf(acc0.y, acc0.y, fmaf(acc1.y, acc1.y, ssq.y));
        ssq.z = fmaf(acc0.z, acc0.z, fmaf(acc1.z, acc1.z, ssq.z));
        ssq.w = fmaf(acc0.w, acc0.w, fmaf(acc1.w, acc1.w, ssq.w));
    }
    // lane l, comp q holds channel j=(4l+q)%6 : constant along lane stride 3
    float vals[8] = {ssum.x, ssum.y, ssum.z, ssum.w, ssq.x, ssq.y, ssq.z, ssq.w};
    #pragma unroll
    for (int q = 0; q < 8; q++) {
        vals[q] += __shfl_down(vals[q], 24, 64);
        vals[q] += __shfl_down(vals[q], 12, 64);
        vals[q] += __shfl_down(vals[q], 6, 64);
        vals[q] += __shfl_down(vals[q], 3, 64);
    }
    __shared__ float red[4][3][8];
    if (lane < 3) {
        #pragma unroll
        for (int q = 0; q < 8; q++) red[wv][lane][q] = vals[q];
    }
    __syncthreads();
    if (tid < 24) {
        int l0 = tid >> 3, qq = tid & 7;
        float v = red[0][l0][qq] + red[1][l0][qq] + red[2][l0][qq] + red[3][l0][qq];
        int j = (4 * l0 + (qq & 3)) % 6;
        atomicAdd(&stats_out[(qq < 4 ? 0 : 6) + j], v);
    }
}

// ---------- GEMM1 (r11 structure): fp32 s_act NC=50; bf16 partials epilogue only ----------
__global__ __launch_bounds__(256) void gemm1_kernel(const unsigned short* __restrict__ agg3,
                                                    const float* __restrict__ stats,
                                                    const float* __restrict__ gam,
                                                    const float* __restrict__ bet,
                                                    const float* __restrict__ lw1,
                                                    unsigned int* __restrict__ partials, int NB) {
    __shared__ float s_act[NC * ROWF];   // 9600 floats = 38.4KB
    int tid = threadIdx.x;
    float inv = 1.f / (float)NB;
    float sa[6], sc[6];
    #pragma unroll
    for (int j = 0; j < 6; j++) {
        float mu = stats[j] * inv;
        float var = stats[6 + j] * inv - mu * mu;
        float rs = rsqrtf(var + BN_EPS);
        float a = gam[j] * rs;
        sa[j] = a; sc[j] = bet[j] - mu * a;
    }
    int n0 = blockIdx.x * NC;
    const unsigned int* ab = (const unsigned int*)(agg3 + (size_t)n0 * ROWF);
    for (int idx = tid; idx < NC * ROWF / 2; idx += 256) {
        unsigned int q = ab[idx];
        float v0 = __uint_as_float(q << 16);
        float v1 = __uint_as_float(q & 0xFFFF0000u);
        int j0 = (2 * idx) % 6;                   // even; j1 = j0+1
        float t0 = fmaf(sa[j0], v0, sc[j0]);
        float t1 = fmaf(sa[j0 + 1], v1, sc[j0 + 1]);
        s_act[2 * idx]     = t0 > 0.f ? t0 : 0.f;
        s_act[2 * idx + 1] = t1 > 0.f ? t1 : 0.f;
    }
    __syncthreads();
    int wv = tid >> 6, lane = tid & 63;
    int b0 = wv * 8;
    float4 acc[8];
    #pragma unroll
    for (int i = 0; i < 8; i++) acc[i] = make_float4(0.f, 0.f, 0.f, 0.f);
    const float* wbase = lw1 + (size_t)n0 * 6 * 256 + 4 * lane;
    for (int nl = 0; nl < NC; nl++) {
        float4 w6[6];
        #pragma unroll
        for (int j = 0; j < 6; j++)
            w6[j] = *(const float4*)(wbase + ((size_t)nl * 6 + j) * 256);
        const float* hb = &s_act[nl * ROWF + b0 * 6];
        #pragma unroll
        for (int bb = 0; bb < 8; bb++) {
            const float* hp = hb + bb * 6;
            float2 h01 = *(const float2*)hp;
            float2 h23 = *(const float2*)(hp + 2);
            float2 h45 = *(const float2*)(hp + 4);
            float4 a = acc[bb];
            a.x = fmaf(h01.x, w6[0].x, a.x); a.y = fmaf(h01.x, w6[0].y, a.y);
            a.z = fmaf(h01.x, w6[0].z, a.z); a.w = fmaf(h01.x, w6[0].w, a.w);
            a.x = fmaf(h01.y, w6[1].x, a.x); a.y = fmaf(h01.y, w6[1].y, a.y);
            a.z = fmaf(h01.y, w6[1].z, a.z); a.w = fmaf(h01.y, w6[1].w, a.w);
            a.x = fmaf(h23.x, w6[2].x, a.x); a.y = fmaf(h23.x, w6[2].y, a.y);
            a.z = fmaf(h23.x, w6[2].z, a.z); a.w = fmaf(h23.x, w6[2].w, a.w);
            a.x = fmaf(h23.y, w6[3].x, a.x); a.y = fmaf(h23.y, w6[3].y, a.y);
            a.z = fmaf(h23.y, w6[3].z, a.z); a.w = fmaf(h23.y, w6[3].w, a.w);
            a.x = fmaf(h45.x, w6[4].x, a.x); a.y = fmaf(h45.x, w6[4].y, a.y);
            a.z = fmaf(h45.x, w6[4].z, a.z); a.w = fmaf(h45.x, w6[4].w, a.w);
            a.x = fmaf(h45.y, w6[5].x, a.x); a.y = fmaf(h45.y, w6[5].y, a.y);
            a.z = fmaf(h45.y, w6[5].z, a.z); a.w = fmaf(h45.y, w6[5].w, a.w);
            acc[bb] = a;
        }
    }
    // epilogue-only bf16 pack: row (split*32 + graph) of 256 bf16 = 128 uints
    #pragma unroll
    for (int bb = 0; bb < 8; bb++) {
        unsigned int* prow = partials + (((size_t)blockIdx.x * BGR) + b0 + bb) * 128;
        *(uint2*)&prow[2 * lane] = make_uint2(bf16pack(acc[bb].x, acc[bb].y),
                                             bf16pack(acc[bb].z, acc[bb].w));
    }
}

// ---------- reduce bf16 partials[GSPLITS][32*128u] -> p2[RGROUPS][32*256] fp32 ----------
__global__ __launch_bounds__(256) void reduce1_kernel(const unsigned int* __restrict__ partials,
                                                      float* __restrict__ p2) {
    int o = blockIdx.x * 256 + threadIdx.x;   // uint index in [0, 4096); grid.x = 16
    int g = blockIdx.y;                        // 0..15
    float a0 = 0.f, a1 = 0.f;
    for (int s = g; s < GSPLITS; s += RGROUPS) {
        unsigned int q = partials[(size_t)s * (BGR * 128) + o];
        a0 += __uint_as_float(q << 16);
        a1 += __uint_as_float(q & 0xFFFF0000u);
    }
    p2[(size_t)g * (BGR * 256) + 2 * o]     = a0;
    p2[(size_t)g * (BGR * 256) + 2 * o + 1] = a1;
}

// ---------- tail: sum 16 groups + lb1/relu, then 256->128->64->32 ----------
__global__ __launch_bounds__(1024) void tail_kernel(const float* __restrict__ p2,
                                                    const float* __restrict__ lb1,
                                                    const float* __restrict__ lw2, const float* __restrict__ lb2,
                                                    const float* __restrict__ lw3, const float* __restrict__ lb3,
                                                    const float* __restrict__ lw4, const float* __restrict__ lb4,
                                                    float* __restrict__ out) {
    __shared__ float red[4][256];
    __shared__ float s1[256], s2[128], s3[64];
    int b = blockIdx.x;
    int tid = threadIdx.x;
    int c = tid & 255, sg = tid >> 8;
    float a = 0.f;
    for (int g = sg; g < RGROUPS; g += 4)
        a += p2[(size_t)g * (BGR * 256) + b * 256 + c];
    red[sg][c] = a;
    __syncthreads();
    if (tid < 256) {
        float v = red[0][tid] + red[1][tid] + red[2][tid] + red[3][tid] + lb1[tid];
        s1[tid] = v > 0.f ? v : 0.f;
    }
    __syncthreads();
    if (tid < 128) {
        float acc = lb2[tid];
        for (int k = 0; k < 256; k++) acc += s1[k] * lw2[k * 128 + tid];
        s2[tid] = acc > 0.f ? acc : 0.f;
    }
    __syncthreads();
    if (tid < 64) {
        float acc = lb3[tid];
        for (int k = 0; k < 128; k++) acc += s2[k] * lw3[k * 64 + tid];
        s3[tid] = acc > 0.f ? acc : 0.f;
    }
    __syncthreads();
    if (tid < 32) {
        float acc = lb4[tid];
        for (int k = 0; k < 64; k++) acc += s3[k] * lw4[k * 32 + tid];
        out[b * 32 + tid] = acc;
    }
}

extern "C" void kernel_launch(void* const* d_in, const int* in_sizes, int n_in,
                              void* d_out, int out_size, void* d_ws, size_t ws_size,
                              hipStream_t stream) {
    const float* x   = (const float*)d_in[0];
    const int* edge  = (const int*)d_in[1];
    const float* W1  = (const float*)d_in[2];
    const float* g1  = (const float*)d_in[4];
    const float* be1 = (const float*)d_in[5];
    const float* W2  = (const float*)d_in[6];
    const float* g2  = (const float*)d_in[8];
    const float* be2 = (const float*)d_in[9];
    const float* W3  = (const float*)d_in[10];
    const float* g3  = (const float*)d_in[12];
    const float* be3 = (const float*)d_in[13];
    const float* lw1 = (const float*)d_in[14];
    const float* lb1 = (const float*)d_in[15];
    const float* lw2 = (const float*)d_in[16];
    const float* lb2 = (const float*)d_in[17];
    const float* lw3 = (const float*)d_in[18];
    const float* lb3 = (const float*)d_in[19];
    const float* lw4 = (const float*)d_in[20];
    const float* lb4 = (const float*)d_in[21];

    const int E = in_sizes[1] / 2;
    const int N = NNODES;
    const int B = in_sizes[0] / (N * 3);
    const int NB = B * N;
    const int nblk = (N + 255) / 256;

    char* ws = (char*)d_ws;
    size_t rowShorts = (size_t)N * ROWF * sizeof(unsigned short);  // 19.2 MB per bf16 buffer
    unsigned short* aggbuf = (unsigned short*)ws;
    unsigned short* mbuf   = (unsigned short*)(ws + rowShorts);
    unsigned int* partials = (unsigned int*)(ws + 2 * rowShorts);  // 1000*32*128u = 16.4 MB
    char* p = ws + 2 * rowShorts + (size_t)GSPLITS * BGR * 128 * 4;
    float* dis    = (float*)p;  p += (size_t)N * 4;
    int*   deg    = (int*)p;    p += (size_t)N * 4;
    int*   offs   = (int*)p;    p += (size_t)(N + 1) * 4;
    int*   cursor = (int*)p;    p += (size_t)N * 4;
    int*   bsum   = (int*)p;    p += 256 * 4;
    int*   bbase  = (int*)p;    p += 256 * 4;
    int2*  csr_rw = (int2*)p;   p += (size_t)E * 8;
    float* stats  = (float*)p;  p += 48 * 4;
    float* p2     = (float*)p;  p += (size_t)RGROUPS * BGR * 256 * 4;
    float* stats1 = stats, *stats2 = stats + 16, *stats3 = stats + 32;

    const int T = 256;

    hipMemsetAsync(deg, 0, (size_t)N * 4, stream);
    hipMemsetAsync(stats, 0, 48 * 4, stream);
    count_deg_kernel<<<(E + T - 1) / T, T, 0, stream>>>(edge + E, E, deg);
    make_dis_kernel<<<(N + T - 1) / T, T, 0, stream>>>(deg, dis, N);
    scanA_kernel<<<nblk, T, 0, stream>>>(deg, bsum, N);
    scanB_kernel<<<1, T, 0, stream>>>(bsum, bbase, offs + N, nblk);
    scanC_kernel<<<nblk, T, 0, stream>>>(deg, bbase, offs, cursor, N);
    fill_csr_kernel<<<(E + T - 1) / T, T, 0, stream>>>(edge, edge + E, dis, cursor, csr_rw, E);

    // layer 1: m1 = x@W1 (bf16) ; agg1 = S m1 (bf16, exact stats)
    t1_kernel<<<(N + 63) / 64, T, 0, stream>>>(x, W1, mbuf, N);
    gather_kernel<<<GATHER_BLOCKS, T, 0, stream>>>(mbuf, offs, csr_rw, dis, aggbuf, stats1, N);
    // layer 2
    t23_kernel<<<(NB + T - 1) / T, T, 0, stream>>>(aggbuf, stats1, g1, be1, W2, mbuf, NB);
    gather_kernel<<<GATHER_BLOCKS, T, 0, stream>>>(mbuf, offs, csr_rw, dis, aggbuf, stats2, N);
    // layer 3
    t23_kernel<<<(NB + T - 1) / T, T, 0, stream>>>(aggbuf, stats2, g2, be2, W3, mbuf, NB);
    gather_kernel<<<GATHER_BLOCKS, T, 0, stream>>>(mbuf, offs, csr_rw, dis, aggbuf, stats3, N);

    // MLP head (bf16 agg3 in, fp32 LDS/math, bf16 partials out; p2/tail fp32)
    gemm1_kernel<<<GSPLITS, T, 0, stream>>>(aggbuf, stats3, g3, be3, lw1, partials, NB);
    reduce1_kernel<<<dim3(16, RGROUPS), T, 0, stream>>>(partials, p2);
    tail_kernel<<<B, 1024, 0, stream>>>(p2, lb1, lw2, lb2, lw3, lb3, lw4, lb4, (float*)d_out);
}